// Round 12
// baseline (281.339 us; speedup 1.0000x reference)
//
#include <hip/hip_runtime.h>
#include <hip/hip_bf16.h>
#include <math.h>

#define B_ 4
#define N_ 32768
#define CIN 6
#define C_ 64
#define R_ 16
#define S_ 4096

typedef __attribute__((ext_vector_type(8))) __bf16 bf16x8;
typedef __attribute__((ext_vector_type(8))) short short8;
typedef __attribute__((ext_vector_type(4))) float f32x4;

#define MFMA16(a, b, c) __builtin_amdgcn_mfma_f32_16x16x32_bf16((a), (b), (c), 0, 0, 0)

__device__ inline f32x4 zero4() {
    f32x4 z;
    z[0] = 0.f; z[1] = 0.f; z[2] = 0.f; z[3] = 0.f;
    return z;
}

__device__ inline unsigned short f2bf(float f) {
    unsigned u = __builtin_bit_cast(unsigned, f);
    u += 0x7fffu + ((u >> 16) & 1u);          // RNE
    return (unsigned short)(u >> 16);
}

__device__ inline float bf2f(unsigned short s) {
    unsigned u = ((unsigned)s) << 16;
    return __builtin_bit_cast(float, u);
}

__device__ inline short8 pack8(float4 a, float4 b) {
    short8 r;
    r[0] = (short)f2bf(a.x); r[1] = (short)f2bf(a.y); r[2] = (short)f2bf(a.z); r[3] = (short)f2bf(a.w);
    r[4] = (short)f2bf(b.x); r[5] = (short)f2bf(b.y); r[6] = (short)f2bf(b.z); r[7] = (short)f2bf(b.w);
    return r;
}

// ---------------- K1: voxelize scatter-add ----------------
__global__ void k_voxelize(const float* __restrict__ coords, const float* __restrict__ feats,
                           float* __restrict__ vsum, float* __restrict__ cnt) {
    int idx = blockIdx.x * 256 + threadIdx.x;
    int b = idx >> 15, n = idx & (N_ - 1);
    const float* cb = coords + (size_t)b * 3 * N_;
    float x = cb[n], y = cb[N_ + n], z = cb[2 * N_ + n];
    int vx = min(max((int)floorf(x * R_), 0), R_ - 1);
    int vy = min(max((int)floorf(y * R_), 0), R_ - 1);
    int vz = min(max((int)floorf(z * R_), 0), R_ - 1);
    int cell = (vx * R_ + vy) * R_ + vz;
    float* vs = vsum + (size_t)b * CIN * S_;
    const float* fb = feats + (size_t)b * CIN * N_;
#pragma unroll
    for (int f = 0; f < CIN; f++) atomicAdd(&vs[f * S_ + cell], fb[f * N_ + n]);
    atomicAdd(&cnt[b * S_ + cell], 1.0f);
}

// ---------------- K2: conv with fused mean-division, LDS-staged slices ----------------
__global__ __launch_bounds__(256) void k_conv2(const float* __restrict__ vsum, const float* __restrict__ cnt,
                                               const float* __restrict__ w, const float* __restrict__ bias,
                                               float* __restrict__ outv) {
    __shared__ float msl[3][CIN][256];
    __shared__ float wl[8 * 162];
    int bid = blockIdx.x;                 // b(4) x x(16) x og(8) = 512
    int b = bid >> 7;
    int x = (bid >> 3) & 15;
    int o0 = (bid & 7) * 8;
    int tid = threadIdx.x;
    for (int i = tid; i < 8 * 162; i += 256) wl[i] = w[o0 * 162 + i];
#pragma unroll
    for (int sl = 0; sl < 3; sl++) {
        int xx = x - 1 + sl;
        if (xx >= 0 && xx < 16) {
            float c = cnt[b * S_ + xx * 256 + tid];
            float invc = 1.f / fmaxf(c, 1.f);
#pragma unroll
            for (int i = 0; i < CIN; i++)
                msl[sl][i][tid] = vsum[((size_t)b * CIN + i) * S_ + xx * 256 + tid] * invc;
        } else {
#pragma unroll
            for (int i = 0; i < CIN; i++) msl[sl][i][tid] = 0.f;
        }
    }
    __syncthreads();
    int y = tid >> 4, z = tid & 15;
    float acc[8];
#pragma unroll
    for (int oj = 0; oj < 8; oj++) acc[oj] = bias[o0 + oj];
#pragma unroll
    for (int dx = 0; dx < 3; dx++) {
#pragma unroll
        for (int dy = 0; dy < 3; dy++) {
            int yy = y + dy - 1;
            if ((unsigned)yy >= 16u) continue;
#pragma unroll
            for (int dz = 0; dz < 3; dz++) {
                int zz = z + dz - 1;
                if ((unsigned)zz >= 16u) continue;
                int idx = yy * 16 + zz;
#pragma unroll
                for (int i = 0; i < CIN; i++) {
                    float m = msl[dx][i][idx];
                    int wb = i * 27 + dx * 9 + dy * 3 + dz;
#pragma unroll
                    for (int oj = 0; oj < 8; oj++) acc[oj] += wl[oj * 162 + wb] * m;
                }
            }
        }
    }
    int cell = x * 256 + tid;
#pragma unroll
    for (int oj = 0; oj < 8; oj++)
        outv[((size_t)b * 64 + o0 + oj) * S_ + cell] = fmaxf(acc[oj], 0.f);
}

// ---------------- K3: qkv -> qT,kT bf16 [b][s][64]; vT bf16 [b][c][t]; voxT f32 [b][s][64] ----------------
__global__ __launch_bounds__(256) void k_qkv3(const float* __restrict__ x, const float* __restrict__ wq,
                                              const float* __restrict__ wk, const float* __restrict__ wv,
                                              unsigned short* __restrict__ qT, unsigned short* __restrict__ kT,
                                              unsigned short* __restrict__ vT, float* __restrict__ voxT) {
    __shared__ float wql[8 * 64], wkl[8 * 64], wvl[8 * 64];
    int bid = blockIdx.x;                 // b(4) x schunk(16) x osplit(8) = 512
    int b = bid >> 7;
    int schunk = (bid >> 3) & 15;
    int o0 = (bid & 7) * 8;
    int tid = threadIdx.x;
    for (int i = tid; i < 512; i += 256) {
        wql[i] = wq[o0 * 64 + i];
        wkl[i] = wk[o0 * 64 + i];
        wvl[i] = wv[o0 * 64 + i];
    }
    __syncthreads();
    int s = schunk * 256 + tid;
    const float* xb = x + (size_t)b * 64 * S_;
    float xr[64];
#pragma unroll
    for (int c = 0; c < 64; c++) xr[c] = xb[c * S_ + s];
    short8 sq, sk;
#pragma unroll
    for (int oj = 0; oj < 8; oj++) {
        float aq = 0.f, ak = 0.f, av = 0.f;
#pragma unroll
        for (int c = 0; c < 64; c++) {
            float xv = xr[c];
            aq += wql[oj * 64 + c] * xv;
            ak += wkl[oj * 64 + c] * xv;
            av += wvl[oj * 64 + c] * xv;
        }
        sq[oj] = (short)f2bf(aq);
        sk[oj] = (short)f2bf(ak);
        vT[((size_t)b * 64 + o0 + oj) * S_ + s] = f2bf(av);
    }
    *(short8*)(qT + ((size_t)b * S_ + s) * 64 + o0) = sq;
    *(short8*)(kT + ((size_t)b * S_ + s) * 64 + o0) = sk;
    if ((bid & 7) == 0) {
        float* vr = voxT + ((size_t)b * S_ + s) * 64;
#pragma unroll
        for (int i = 0; i < 16; i++)
            *(float4*)(vr + i * 4) = make_float4(xr[i * 4], xr[i * 4 + 1], xr[i * 4 + 2], xr[i * 4 + 3]);
    }
}

// ---------------- K4: attn — 8 waves x 512-t splits of same 32 q-rows, aliased LDS, fused epilogue ----------------
__global__ __launch_bounds__(512, 4) void k_attn10(const unsigned short* __restrict__ qT,
                                                   const unsigned short* __restrict__ kT,
                                                   const unsigned short* __restrict__ vT,
                                                   const float* __restrict__ wo,
                                                   const float* __restrict__ voxT,
                                                   unsigned short* __restrict__ xattT,
                                                   float* __restrict__ semean) {
    __shared__ __align__(16) char sbuf[32768];   // loop: Ps[8][4KB]; after: Oc[4][8KB] f32
    __shared__ unsigned short PA[2048];          // 4KB normalized bf16 A-frags
    __shared__ float lc[8][32];
    __shared__ float sem[64];
    int bid = blockIdx.x;                        // 512: b(4) x qtile(128)
    int b = bid >> 7;
    int sq0 = (bid & 127) * 32;
    int tid = threadIdx.x;
    int w = tid >> 6, lane = tid & 63;
    int lo = lane & 15, hi = lane >> 4;
    if (tid < 64) sem[tid] = 0.f;
    unsigned short* Ps = (unsigned short*)(sbuf + w * 4096);

    // Q fragments for 2 sub-tiles of 16 rows (same 32 rows for all 8 waves)
    const unsigned short* qb = qT + ((size_t)b * S_ + sq0) * 64;
    bf16x8 qf00 = __builtin_bit_cast(bf16x8, *(const short8*)(qb + lo * 64 + hi * 8));
    bf16x8 qf01 = __builtin_bit_cast(bf16x8, *(const short8*)(qb + lo * 64 + hi * 8 + 32));
    bf16x8 qf10 = __builtin_bit_cast(bf16x8, *(const short8*)(qb + (16 + lo) * 64 + hi * 8));
    bf16x8 qf11 = __builtin_bit_cast(bf16x8, *(const short8*)(qb + (16 + lo) * 64 + hi * 8 + 32));

    f32x4 O[8];
    float l[8];
#pragma unroll
    for (int i = 0; i < 8; i++) O[i] = zero4();
#pragma unroll
    for (int i = 0; i < 8; i++) l[i] = 0.f;

    const unsigned short* kb = kT + (size_t)b * S_ * 64 + hi * 8;
    const unsigned short* vb = vT + (size_t)b * 64 * S_;

    for (int t0 = w * 512; t0 < w * 512 + 512; t0 += 64) {
        // ---- V loads first: independent, hide under QK + softmax ----
        short8 vfa0, vfb0, vfa1, vfb1, vfa2, vfb2, vfa3, vfb3;
        {
            const unsigned short* vr0 = vb + (size_t)(0 + lo) * S_ + t0 + hi * 8;
            const unsigned short* vr1 = vb + (size_t)(16 + lo) * S_ + t0 + hi * 8;
            const unsigned short* vr2 = vb + (size_t)(32 + lo) * S_ + t0 + hi * 8;
            const unsigned short* vr3 = vb + (size_t)(48 + lo) * S_ + t0 + hi * 8;
            vfa0 = *(const short8*)vr0; vfb0 = *(const short8*)(vr0 + 32);
            vfa1 = *(const short8*)vr1; vfb1 = *(const short8*)(vr1 + 32);
            vfa2 = *(const short8*)vr2; vfb2 = *(const short8*)(vr2 + 32);
            vfa3 = *(const short8*)vr3; vfb3 = *(const short8*)(vr3 + 32);
        }
        // ---- QK^T + fixed-max softmax, per 16-col tile ----
#pragma unroll
        for (int ct = 0; ct < 4; ct++) {
            const unsigned short* kr = kb + (size_t)(t0 + ct * 16 + lo) * 64;
            bf16x8 kf0 = __builtin_bit_cast(bf16x8, *(const short8*)kr);
            bf16x8 kf1 = __builtin_bit_cast(bf16x8, *(const short8*)(kr + 32));
#pragma unroll
            for (int qs = 0; qs < 2; qs++) {
                f32x4 z = zero4();
                z = MFMA16(qs ? qf10 : qf00, kf0, z);
                f32x4 Sacc = MFMA16(qs ? qf11 : qf01, kf1, z);
#pragma unroll
                for (int j = 0; j < 4; j++) {
                    float p = __expf(Sacc[j] * 0.125f);
                    l[qs * 4 + j] += p;
                    int r = qs * 16 + hi * 4 + j;
                    int swz = (r & 7) << 4;
                    *(unsigned short*)((char*)Ps + ((r * 128 + (ct * 16 + lo) * 2) ^ swz)) = f2bf(p);
                }
            }
        }
        // ---- PV: P A-frags from LDS (same-wave ordering), V frags in regs ----
#pragma unroll
        for (int qs = 0; qs < 2; qs++) {
            int row = qs * 16 + lo;
            int swz2 = (row & 7) << 4;
            bf16x8 pa0 = __builtin_bit_cast(bf16x8, *(const short8*)((char*)Ps + ((row * 128 + hi * 16) ^ swz2)));
            bf16x8 pa1 = __builtin_bit_cast(bf16x8, *(const short8*)((char*)Ps + ((row * 128 + 64 + hi * 16) ^ swz2)));
            O[qs * 4 + 0] = MFMA16(pa0, __builtin_bit_cast(bf16x8, vfa0), O[qs * 4 + 0]);
            O[qs * 4 + 0] = MFMA16(pa1, __builtin_bit_cast(bf16x8, vfb0), O[qs * 4 + 0]);
            O[qs * 4 + 1] = MFMA16(pa0, __builtin_bit_cast(bf16x8, vfa1), O[qs * 4 + 1]);
            O[qs * 4 + 1] = MFMA16(pa1, __builtin_bit_cast(bf16x8, vfb1), O[qs * 4 + 1]);
            O[qs * 4 + 2] = MFMA16(pa0, __builtin_bit_cast(bf16x8, vfa2), O[qs * 4 + 2]);
            O[qs * 4 + 2] = MFMA16(pa1, __builtin_bit_cast(bf16x8, vfb2), O[qs * 4 + 2]);
            O[qs * 4 + 3] = MFMA16(pa0, __builtin_bit_cast(bf16x8, vfa3), O[qs * 4 + 3]);
            O[qs * 4 + 3] = MFMA16(pa1, __builtin_bit_cast(bf16x8, vfb3), O[qs * 4 + 3]);
        }
    }

    // ---- row sums -> lc ----
#pragma unroll
    for (int qs = 0; qs < 2; qs++)
#pragma unroll
        for (int j = 0; j < 4; j++) {
            float s = l[qs * 4 + j];
            s += __shfl_xor(s, 1);
            s += __shfl_xor(s, 2);
            s += __shfl_xor(s, 4);
            s += __shfl_xor(s, 8);
            if (lo == 0) lc[w][qs * 16 + hi * 4 + j] = s;
        }
    __syncthreads();    // all Ps reads done; sbuf can be reused as Oc

    // ---- combine tree: waves 0-3 store into Oc[w]; then waves 4-7 add into Oc[w-4] ----
    if (w < 4) {
        float* dst = (float*)(sbuf + w * 8192);
#pragma unroll
        for (int qs = 0; qs < 2; qs++)
#pragma unroll
            for (int cc = 0; cc < 4; cc++)
#pragma unroll
                for (int j = 0; j < 4; j++)
                    dst[(qs * 16 + hi * 4 + j) * 64 + cc * 16 + lo] = O[qs * 4 + cc][j];
    }
    __syncthreads();
    if (w >= 4) {
        float* dst = (float*)(sbuf + (w - 4) * 8192);
#pragma unroll
        for (int qs = 0; qs < 2; qs++)
#pragma unroll
            for (int cc = 0; cc < 4; cc++)
#pragma unroll
                for (int j = 0; j < 4; j++) {
                    float* p = &dst[(qs * 16 + hi * 4 + j) * 64 + cc * 16 + lo];
                    *p = *p + O[qs * 4 + cc][j];
                }
    }
    __syncthreads();

    // ---- combine 4 buffers, normalize -> PA bf16 (swizzled) ----
    if (tid < 256) {
        int row = tid >> 3;                  // 0..31
        int c0 = (tid & 7) * 8;
        float L = lc[0][row] + lc[1][row] + lc[2][row] + lc[3][row] +
                  lc[4][row] + lc[5][row] + lc[6][row] + lc[7][row];
        float inv = 1.f / L;
        const float* O0 = (const float*)(sbuf);
        const float* O1 = (const float*)(sbuf + 8192);
        const float* O2 = (const float*)(sbuf + 16384);
        const float* O3 = (const float*)(sbuf + 24576);
        int base = row * 64 + c0;
        float4 u0, u1;
        u0.x = (O0[base + 0] + O1[base + 0] + O2[base + 0] + O3[base + 0]) * inv;
        u0.y = (O0[base + 1] + O1[base + 1] + O2[base + 1] + O3[base + 1]) * inv;
        u0.z = (O0[base + 2] + O1[base + 2] + O2[base + 2] + O3[base + 2]) * inv;
        u0.w = (O0[base + 3] + O1[base + 3] + O2[base + 3] + O3[base + 3]) * inv;
        u1.x = (O0[base + 4] + O1[base + 4] + O2[base + 4] + O3[base + 4]) * inv;
        u1.y = (O0[base + 5] + O1[base + 5] + O2[base + 5] + O3[base + 5]) * inv;
        u1.z = (O0[base + 6] + O1[base + 6] + O2[base + 6] + O3[base + 6]) * inv;
        u1.w = (O0[base + 7] + O1[base + 7] + O2[base + 7] + O3[base + 7]) * inv;
        *(short8*)((char*)PA + ((row * 128 + c0 * 2) ^ ((row & 7) << 4))) = pack8(u0, u1);
    }
    __syncthreads();

    // ---- epilogue: waves 0,1 -> Wo MFMA (16 rows each) + residual + SE-mean ----
    if (w < 2) {
        int rl = w * 16 + lo;
        int aswz = (rl & 7) << 4;
        bf16x8 a0 = __builtin_bit_cast(bf16x8, *(const short8*)((char*)PA + ((rl * 128 + hi * 16) ^ aswz)));
        bf16x8 a1 = __builtin_bit_cast(bf16x8, *(const short8*)((char*)PA + ((rl * 128 + 64 + hi * 16) ^ aswz)));
        size_t grow0 = (size_t)b * S_ + sq0 + w * 16;
        float colsum[4];
#pragma unroll
        for (int cc = 0; cc < 4; cc++) {
            int o = cc * 16 + lo;
            float4 f0 = *(const float4*)(wo + o * 64 + hi * 8);
            float4 f1 = *(const float4*)(wo + o * 64 + hi * 8 + 4);
            bf16x8 b0 = __builtin_bit_cast(bf16x8, pack8(f0, f1));
            float4 f2 = *(const float4*)(wo + o * 64 + 32 + hi * 8);
            float4 f3 = *(const float4*)(wo + o * 64 + 32 + hi * 8 + 4);
            bf16x8 b1 = __builtin_bit_cast(bf16x8, pack8(f2, f3));
            f32x4 acc = zero4();
            acc = MFMA16(a0, b0, acc);
            acc = MFMA16(a1, b1, acc);
            float cs = 0.f;
#pragma unroll
            for (int j = 0; j < 4; j++) {
                size_t idx = (grow0 + hi * 4 + j) * 64 + o;
                float xn = acc[j] + voxT[idx];
                xattT[idx] = f2bf(xn);
                cs += xn;
            }
            cs += __shfl_xor(cs, 16);
            cs += __shfl_xor(cs, 32);
            colsum[cc] = cs;
        }
        if (hi == 0) {
#pragma unroll
            for (int cc = 0; cc < 4; cc++) atomicAdd(&sem[cc * 16 + lo], colsum[cc]);
        }
    }
    __syncthreads();
    if (tid < 64) atomicAdd(&semean[b * 64 + tid], sem[tid]);
}

// ---------------- K8: SE gate + devoxelize (bf16 gather) + point MLP + MFMA classifier ----------------
__global__ __launch_bounds__(256) void k_point(const float* __restrict__ coords, const float* __restrict__ feats,
                                               const unsigned short* __restrict__ xt, const float* __restrict__ semean,
                                               const float* __restrict__ sw1, const float* __restrict__ sb1,
                                               const float* __restrict__ sw2, const float* __restrict__ sb2,
                                               const float* __restrict__ pw,
                                               const float* __restrict__ pb, const float* __restrict__ w1,
                                               const float* __restrict__ b1, const float* __restrict__ w2,
                                               const float* __restrict__ b2, float* __restrict__ out) {
    __shared__ unsigned short fl[256 * 64];    // 32KB fused bf16, XOR-swizzled rows
    __shared__ float pwl[64 * 6];
    __shared__ float pbl[64];
    __shared__ float b1l[128];
    __shared__ float w2l[3 * 128];
    __shared__ float b2l[3];
    __shared__ float gl[64];
    __shared__ float sml[64];
    __shared__ float hh[8];
    int tid = threadIdx.x;
    int gidx0 = blockIdx.x * 256;
    int b = gidx0 >> 15, n0 = gidx0 & (N_ - 1);
    int n = n0 + tid;
    for (int i = tid; i < 384; i += 256) { pwl[i] = pw[i]; w2l[i] = w2[i]; }
    if (tid < 128) b1l[tid] = b1[tid];
    if (tid < 64) { pbl[tid] = pb[tid]; sml[tid] = semean[b * 64 + tid] * (1.0f / S_); }
    if (tid < 3) b2l[tid] = b2[tid];
    __syncthreads();
    if (tid < 8) {
        float a = sb1[tid];
#pragma unroll
        for (int i = 0; i < 64; i++) a += sw1[tid * 64 + i] * sml[i];
        hh[tid] = fmaxf(a, 0.f);
    }
    __syncthreads();
    if (tid < 64) {
        float g = sb2[tid];
#pragma unroll
        for (int j = 0; j < 8; j++) g += sw2[tid * 8 + j] * hh[j];
        gl[tid] = 1.f / (1.f + __expf(-g));
    }
    __syncthreads();

    const float* cb = coords + (size_t)b * 3 * N_;
    float px = fminf(fmaxf(cb[n] * R_ - 0.5f, 0.f), 15.f);
    float py = fminf(fmaxf(cb[N_ + n] * R_ - 0.5f, 0.f), 15.f);
    float pz = fminf(fmaxf(cb[2 * N_ + n] * R_ - 0.5f, 0.f), 15.f);
    int x0 = (int)floorf(px); float wx = px - x0; int x1 = min(x0 + 1, 15);
    int y0 = (int)floorf(py); float wy = py - y0; int y1 = min(y0 + 1, 15);
    int z0 = (int)floorf(pz); float wz = pz - z0; int z1 = min(z0 + 1, 15);
    float fused[64];
#pragma unroll
    for (int c = 0; c < 64; c++) fused[c] = 0.f;
    const unsigned short* xb = xt + (size_t)b * S_ * 64;
#pragma unroll
    for (int dx = 0; dx < 2; dx++) {
#pragma unroll
        for (int dy = 0; dy < 2; dy++) {
#pragma unroll
            for (int dz = 0; dz < 2; dz++) {
                int xi = dx ? x1 : x0, yi = dy ? y1 : y0, zi = dz ? z1 : z0;
                float wgt = (dx ? wx : 1.f - wx) * (dy ? wy : 1.f - wy) * (dz ? wz : 1.f - wz);
                const short8* g = (const short8*)(xb + (size_t)((xi * 16 + yi) * 16 + zi) * 64);
#pragma unroll
                for (int c8 = 0; c8 < 8; c8++) {
                    short8 gv = g[c8];
#pragma unroll
                    for (int i = 0; i < 8; i++)
                        fused[c8 * 8 + i] += wgt * bf2f((unsigned short)gv[i]);
                }
            }
        }
    }
    float fv[6];
#pragma unroll
    for (int i = 0; i < 6; i++) fv[i] = feats[((size_t)b * 6 + i) * N_ + n];
#pragma unroll
    for (int c = 0; c < 64; c++) {
        float pt = pbl[c];
#pragma unroll
        for (int i = 0; i < 6; i++) pt += pwl[c * 6 + i] * fv[i];
        pt = fmaxf(pt, 0.f);
        fused[c] = fmaxf(fused[c] * gl[c] + pt, 0.f);
    }
#pragma unroll
    for (int ch = 0; ch < 8; ch++) {
        short8 v;
#pragma unroll
        for (int i = 0; i < 8; i++) v[i] = (short)f2bf(fused[ch * 8 + i]);
        int byte = tid * 128 + ch * 16;
        *(short8*)((char*)fl + (byte ^ ((tid & 7) << 4))) = v;
    }
    __syncthreads();

    int wv = tid >> 6, lane = tid & 63;
    int lo = lane & 15, hi = lane >> 4;
    bf16x8 bw[16];
#pragma unroll
    for (int th = 0; th < 8; th++) {
#pragma unroll
        for (int kf = 0; kf < 2; kf++) {
            const float* wr = w1 + (th * 16 + lo) * 64 + kf * 32 + hi * 8;
            bw[th * 2 + kf] = __builtin_bit_cast(bf16x8, pack8(*(const float4*)wr, *(const float4*)(wr + 4)));
        }
    }
#pragma unroll
    for (int g = 0; g < 4; g++) {
        int row = wv * 64 + g * 16 + lo;
        int swz = (row & 7) << 4;
        bf16x8 a0 = __builtin_bit_cast(bf16x8, *(const short8*)((char*)fl + ((row * 128 + hi * 16) ^ swz)));
        bf16x8 a1 = __builtin_bit_cast(bf16x8, *(const short8*)((char*)fl + ((row * 128 + 64 + hi * 16) ^ swz)));
        f32x4 acc[8];
#pragma unroll
        for (int th = 0; th < 8; th++) {
            acc[th] = zero4();
            acc[th] = MFMA16(a0, bw[th * 2], acc[th]);
            acc[th] = MFMA16(a1, bw[th * 2 + 1], acc[th]);
        }
        float s0[4] = {0.f, 0.f, 0.f, 0.f};
        float s1[4] = {0.f, 0.f, 0.f, 0.f};
        float s2[4] = {0.f, 0.f, 0.f, 0.f};
#pragma unroll
        for (int th = 0; th < 8; th++) {
            int hidx = th * 16 + lo;
            float w2o0 = w2l[hidx];
            float w2o1 = w2l[128 + hidx];
            float w2o2 = w2l[256 + hidx];
            float bias = b1l[hidx];
#pragma unroll
            for (int j = 0; j < 4; j++) {
                float hj = fmaxf(acc[th][j] + bias, 0.f);
                s0[j] += hj * w2o0;
                s1[j] += hj * w2o1;
                s2[j] += hj * w2o2;
            }
        }
#pragma unroll
        for (int j = 0; j < 4; j++) {
            s0[j] += __shfl_xor(s0[j], 1); s0[j] += __shfl_xor(s0[j], 2);
            s0[j] += __shfl_xor(s0[j], 4); s0[j] += __shfl_xor(s0[j], 8);
            s1[j] += __shfl_xor(s1[j], 1); s1[j] += __shfl_xor(s1[j], 2);
            s1[j] += __shfl_xor(s1[j], 4); s1[j] += __shfl_xor(s1[j], 8);
            s2[j] += __shfl_xor(s2[j], 1); s2[j] += __shfl_xor(s2[j], 2);
            s2[j] += __shfl_xor(s2[j], 4); s2[j] += __shfl_xor(s2[j], 8);
        }
        int nbase = n0 + wv * 64 + g * 16 + hi * 4;
        if (lo == 0) {
            float4 o4 = make_float4(s0[0] + b2l[0], s0[1] + b2l[0], s0[2] + b2l[0], s0[3] + b2l[0]);
            *(float4*)(out + ((size_t)b * 3 + 0) * N_ + nbase) = o4;
        } else if (lo == 1) {
            float4 o4 = make_float4(s1[0] + b2l[1], s1[1] + b2l[1], s1[2] + b2l[1], s1[3] + b2l[1]);
            *(float4*)(out + ((size_t)b * 3 + 1) * N_ + nbase) = o4;
        } else if (lo == 2) {
            float4 o4 = make_float4(s2[0] + b2l[2], s2[1] + b2l[2], s2[2] + b2l[2], s2[3] + b2l[2]);
            *(float4*)(out + ((size_t)b * 3 + 2) * N_ + nbase) = o4;
        }
    }
}

extern "C" void kernel_launch(void* const* d_in, const int* in_sizes, int n_in,
                              void* d_out, int out_size, void* d_ws, size_t ws_size,
                              hipStream_t stream) {
    const float* coords  = (const float*)d_in[0];
    const float* feats   = (const float*)d_in[1];
    const float* conv_w  = (const float*)d_in[2];
    const float* conv_b  = (const float*)d_in[3];
    const float* wq      = (const float*)d_in[4];
    const float* wk      = (const float*)d_in[5];
    const float* wv      = (const float*)d_in[6];
    const float* wo      = (const float*)d_in[7];
    const float* se_w1   = (const float*)d_in[8];
    const float* se_b1   = (const float*)d_in[9];
    const float* se_w2   = (const float*)d_in[10];
    const float* se_b2   = (const float*)d_in[11];
    const float* point_w = (const float*)d_in[12];
    const float* point_b = (const float*)d_in[13];
    const float* cls_w1  = (const float*)d_in[14];
    const float* cls_b1  = (const float*)d_in[15];
    const float* cls_w2  = (const float*)d_in[16];
    const float* cls_b2  = (const float*)d_in[17];

    float* ws = (float*)d_ws;
    float* vsum   = ws;                        // 98304
    float* cnt    = ws + 98304;                // 16384
    float* semean = ws + 114688;               // 256
    float* vox    = ws + 115200;               // 1048576 [conv2 -> qkv3]; reused as xattT (bf16)
    float* voxT   = vox + 1048576;             // 1048576 [qkv3 -> attn epilogue residual]
    unsigned short* qT = (unsigned short*)(voxT + 1048576);
    unsigned short* kT = qT + 1048576;
    unsigned short* vT = kT + 1048576;
    unsigned short* xattT = (unsigned short*)vox;   // bf16 [b][s][64]; vox dead after qkv3

    hipMemsetAsync(ws, 0, 114944 * sizeof(float), stream);    // vsum + cnt + semean
    k_voxelize<<<512, 256, 0, stream>>>(coords, feats, vsum, cnt);
    k_conv2<<<512, 256, 0, stream>>>(vsum, cnt, conv_w, conv_b, vox);
    k_qkv3<<<512, 256, 0, stream>>>(vox, wq, wk, wv, qT, kT, vT, voxT);
    k_attn10<<<512, 512, 0, stream>>>(qT, kT, vT, wo, voxT, xattT, semean);
    k_point<<<512, 256, 0, stream>>>(coords, feats, xattT, semean,
                                     se_w1, se_b1, se_w2, se_b2, point_w, point_b,
                                     cls_w1, cls_b1, cls_w2, cls_b2, (float*)d_out);
}

// Round 13
// 227.976 us; speedup vs baseline: 1.2341x; 1.2341x over previous
//
#include <hip/hip_runtime.h>
#include <hip/hip_bf16.h>
#include <math.h>

#define B_ 4
#define N_ 32768
#define CIN 6
#define C_ 64
#define R_ 16
#define S_ 4096

typedef __attribute__((ext_vector_type(8))) __bf16 bf16x8;
typedef __attribute__((ext_vector_type(8))) short short8;
typedef __attribute__((ext_vector_type(4))) float f32x4;

#define MFMA16(a, b, c) __builtin_amdgcn_mfma_f32_16x16x32_bf16((a), (b), (c), 0, 0, 0)

__device__ inline f32x4 zero4() {
    f32x4 z;
    z[0] = 0.f; z[1] = 0.f; z[2] = 0.f; z[3] = 0.f;
    return z;
}

__device__ inline unsigned short f2bf(float f) {
    unsigned u = __builtin_bit_cast(unsigned, f);
    u += 0x7fffu + ((u >> 16) & 1u);          // RNE
    return (unsigned short)(u >> 16);
}

__device__ inline float bf2f(unsigned short s) {
    unsigned u = ((unsigned)s) << 16;
    return __builtin_bit_cast(float, u);
}

__device__ inline short8 pack8(float4 a, float4 b) {
    short8 r;
    r[0] = (short)f2bf(a.x); r[1] = (short)f2bf(a.y); r[2] = (short)f2bf(a.z); r[3] = (short)f2bf(a.w);
    r[4] = (short)f2bf(b.x); r[5] = (short)f2bf(b.y); r[6] = (short)f2bf(b.z); r[7] = (short)f2bf(b.w);
    return r;
}

// ---------------- K1: voxelize scatter-add ----------------
__global__ void k_voxelize(const float* __restrict__ coords, const float* __restrict__ feats,
                           float* __restrict__ vsum, float* __restrict__ cnt) {
    int idx = blockIdx.x * 256 + threadIdx.x;
    int b = idx >> 15, n = idx & (N_ - 1);
    const float* cb = coords + (size_t)b * 3 * N_;
    float x = cb[n], y = cb[N_ + n], z = cb[2 * N_ + n];
    int vx = min(max((int)floorf(x * R_), 0), R_ - 1);
    int vy = min(max((int)floorf(y * R_), 0), R_ - 1);
    int vz = min(max((int)floorf(z * R_), 0), R_ - 1);
    int cell = (vx * R_ + vy) * R_ + vz;
    float* vs = vsum + (size_t)b * CIN * S_;
    const float* fb = feats + (size_t)b * CIN * N_;
#pragma unroll
    for (int f = 0; f < CIN; f++) atomicAdd(&vs[f * S_ + cell], fb[f * N_ + n]);
    atomicAdd(&cnt[b * S_ + cell], 1.0f);
}

// ---------------- K2: conv with fused mean-division, LDS-staged slices ----------------
__global__ __launch_bounds__(256) void k_conv2(const float* __restrict__ vsum, const float* __restrict__ cnt,
                                               const float* __restrict__ w, const float* __restrict__ bias,
                                               float* __restrict__ outv) {
    __shared__ float msl[3][CIN][256];
    __shared__ float wl[8 * 162];
    int bid = blockIdx.x;                 // b(4) x x(16) x og(8) = 512
    int b = bid >> 7;
    int x = (bid >> 3) & 15;
    int o0 = (bid & 7) * 8;
    int tid = threadIdx.x;
    for (int i = tid; i < 8 * 162; i += 256) wl[i] = w[o0 * 162 + i];
#pragma unroll
    for (int sl = 0; sl < 3; sl++) {
        int xx = x - 1 + sl;
        if (xx >= 0 && xx < 16) {
            float c = cnt[b * S_ + xx * 256 + tid];
            float invc = 1.f / fmaxf(c, 1.f);
#pragma unroll
            for (int i = 0; i < CIN; i++)
                msl[sl][i][tid] = vsum[((size_t)b * CIN + i) * S_ + xx * 256 + tid] * invc;
        } else {
#pragma unroll
            for (int i = 0; i < CIN; i++) msl[sl][i][tid] = 0.f;
        }
    }
    __syncthreads();
    int y = tid >> 4, z = tid & 15;
    float acc[8];
#pragma unroll
    for (int oj = 0; oj < 8; oj++) acc[oj] = bias[o0 + oj];
#pragma unroll
    for (int dx = 0; dx < 3; dx++) {
#pragma unroll
        for (int dy = 0; dy < 3; dy++) {
            int yy = y + dy - 1;
            if ((unsigned)yy >= 16u) continue;
#pragma unroll
            for (int dz = 0; dz < 3; dz++) {
                int zz = z + dz - 1;
                if ((unsigned)zz >= 16u) continue;
                int idx = yy * 16 + zz;
#pragma unroll
                for (int i = 0; i < CIN; i++) {
                    float m = msl[dx][i][idx];
                    int wb = i * 27 + dx * 9 + dy * 3 + dz;
#pragma unroll
                    for (int oj = 0; oj < 8; oj++) acc[oj] += wl[oj * 162 + wb] * m;
                }
            }
        }
    }
    int cell = x * 256 + tid;
#pragma unroll
    for (int oj = 0; oj < 8; oj++)
        outv[((size_t)b * 64 + o0 + oj) * S_ + cell] = fmaxf(acc[oj], 0.f);
}

// ---------------- K3: qkv -> qT,kT bf16 [b][s][64]; vT bf16 [b][c][t]; voxT f32 [b][s][64] ----------------
__global__ __launch_bounds__(256) void k_qkv3(const float* __restrict__ x, const float* __restrict__ wq,
                                              const float* __restrict__ wk, const float* __restrict__ wv,
                                              unsigned short* __restrict__ qT, unsigned short* __restrict__ kT,
                                              unsigned short* __restrict__ vT, float* __restrict__ voxT) {
    __shared__ float wql[8 * 64], wkl[8 * 64], wvl[8 * 64];
    int bid = blockIdx.x;                 // b(4) x schunk(16) x osplit(8) = 512
    int b = bid >> 7;
    int schunk = (bid >> 3) & 15;
    int o0 = (bid & 7) * 8;
    int tid = threadIdx.x;
    for (int i = tid; i < 512; i += 256) {
        wql[i] = wq[o0 * 64 + i];
        wkl[i] = wk[o0 * 64 + i];
        wvl[i] = wv[o0 * 64 + i];
    }
    __syncthreads();
    int s = schunk * 256 + tid;
    const float* xb = x + (size_t)b * 64 * S_;
    float xr[64];
#pragma unroll
    for (int c = 0; c < 64; c++) xr[c] = xb[c * S_ + s];
    short8 sq, sk;
#pragma unroll
    for (int oj = 0; oj < 8; oj++) {
        float aq = 0.f, ak = 0.f, av = 0.f;
#pragma unroll
        for (int c = 0; c < 64; c++) {
            float xv = xr[c];
            aq += wql[oj * 64 + c] * xv;
            ak += wkl[oj * 64 + c] * xv;
            av += wvl[oj * 64 + c] * xv;
        }
        sq[oj] = (short)f2bf(aq);
        sk[oj] = (short)f2bf(ak);
        vT[((size_t)b * 64 + o0 + oj) * S_ + s] = f2bf(av);
    }
    *(short8*)(qT + ((size_t)b * S_ + s) * 64 + o0) = sq;
    *(short8*)(kT + ((size_t)b * S_ + s) * 64 + o0) = sk;
    if ((bid & 7) == 0) {
        float* vr = voxT + ((size_t)b * S_ + s) * 64;
#pragma unroll
        for (int i = 0; i < 16; i++)
            *(float4*)(vr + i * 4) = make_float4(xr[i * 4], xr[i * 4 + 1], xr[i * 4 + 2], xr[i * 4 + 3]);
    }
}

// ---------------- K4: attn — 8 waves x 512-t splits of same 32 q-rows, aliased LDS, fused epilogue ----------------
__global__ __launch_bounds__(512, 2) void k_attn10(const unsigned short* __restrict__ qT,
                                                   const unsigned short* __restrict__ kT,
                                                   const unsigned short* __restrict__ vT,
                                                   const float* __restrict__ wo,
                                                   const float* __restrict__ voxT,
                                                   unsigned short* __restrict__ xattT,
                                                   float* __restrict__ semean) {
    __shared__ __align__(16) char sbuf[32768];   // loop: Ps[8][4KB]; after: Oc[4][8KB] f32
    __shared__ unsigned short PA[2048];          // 4KB normalized bf16 A-frags
    __shared__ float lc[8][32];
    __shared__ float sem[64];
    int bid = blockIdx.x;                        // 512: b(4) x qtile(128)
    int b = bid >> 7;
    int sq0 = (bid & 127) * 32;
    int tid = threadIdx.x;
    int w = tid >> 6, lane = tid & 63;
    int lo = lane & 15, hi = lane >> 4;
    if (tid < 64) sem[tid] = 0.f;
    unsigned short* Ps = (unsigned short*)(sbuf + w * 4096);

    // Q fragments for 2 sub-tiles of 16 rows (same 32 rows for all 8 waves)
    const unsigned short* qb = qT + ((size_t)b * S_ + sq0) * 64;
    bf16x8 qf00 = __builtin_bit_cast(bf16x8, *(const short8*)(qb + lo * 64 + hi * 8));
    bf16x8 qf01 = __builtin_bit_cast(bf16x8, *(const short8*)(qb + lo * 64 + hi * 8 + 32));
    bf16x8 qf10 = __builtin_bit_cast(bf16x8, *(const short8*)(qb + (16 + lo) * 64 + hi * 8));
    bf16x8 qf11 = __builtin_bit_cast(bf16x8, *(const short8*)(qb + (16 + lo) * 64 + hi * 8 + 32));

    f32x4 O[8];
    float l[8];
#pragma unroll
    for (int i = 0; i < 8; i++) O[i] = zero4();
#pragma unroll
    for (int i = 0; i < 8; i++) l[i] = 0.f;

    const unsigned short* kb = kT + (size_t)b * S_ * 64 + hi * 8;
    const unsigned short* vb = vT + (size_t)b * 64 * S_;

    for (int t0 = w * 512; t0 < w * 512 + 512; t0 += 64) {
        // ---- V loads first: independent, hide under QK + softmax ----
        short8 vfa0, vfb0, vfa1, vfb1, vfa2, vfb2, vfa3, vfb3;
        {
            const unsigned short* vr0 = vb + (size_t)(0 + lo) * S_ + t0 + hi * 8;
            const unsigned short* vr1 = vb + (size_t)(16 + lo) * S_ + t0 + hi * 8;
            const unsigned short* vr2 = vb + (size_t)(32 + lo) * S_ + t0 + hi * 8;
            const unsigned short* vr3 = vb + (size_t)(48 + lo) * S_ + t0 + hi * 8;
            vfa0 = *(const short8*)vr0; vfb0 = *(const short8*)(vr0 + 32);
            vfa1 = *(const short8*)vr1; vfb1 = *(const short8*)(vr1 + 32);
            vfa2 = *(const short8*)vr2; vfb2 = *(const short8*)(vr2 + 32);
            vfa3 = *(const short8*)vr3; vfb3 = *(const short8*)(vr3 + 32);
        }
        // ---- QK^T + fixed-max softmax, per 16-col tile ----
#pragma unroll
        for (int ct = 0; ct < 4; ct++) {
            const unsigned short* kr = kb + (size_t)(t0 + ct * 16 + lo) * 64;
            bf16x8 kf0 = __builtin_bit_cast(bf16x8, *(const short8*)kr);
            bf16x8 kf1 = __builtin_bit_cast(bf16x8, *(const short8*)(kr + 32));
#pragma unroll
            for (int qs = 0; qs < 2; qs++) {
                f32x4 z = zero4();
                z = MFMA16(qs ? qf10 : qf00, kf0, z);
                f32x4 Sacc = MFMA16(qs ? qf11 : qf01, kf1, z);
#pragma unroll
                for (int j = 0; j < 4; j++) {
                    float p = __expf(Sacc[j] * 0.125f);
                    l[qs * 4 + j] += p;
                    int r = qs * 16 + hi * 4 + j;
                    int swz = (r & 7) << 4;
                    *(unsigned short*)((char*)Ps + ((r * 128 + (ct * 16 + lo) * 2) ^ swz)) = f2bf(p);
                }
            }
        }
        // ---- PV: P A-frags from LDS (same-wave ordering), V frags in regs ----
#pragma unroll
        for (int qs = 0; qs < 2; qs++) {
            int row = qs * 16 + lo;
            int swz2 = (row & 7) << 4;
            bf16x8 pa0 = __builtin_bit_cast(bf16x8, *(const short8*)((char*)Ps + ((row * 128 + hi * 16) ^ swz2)));
            bf16x8 pa1 = __builtin_bit_cast(bf16x8, *(const short8*)((char*)Ps + ((row * 128 + 64 + hi * 16) ^ swz2)));
            O[qs * 4 + 0] = MFMA16(pa0, __builtin_bit_cast(bf16x8, vfa0), O[qs * 4 + 0]);
            O[qs * 4 + 0] = MFMA16(pa1, __builtin_bit_cast(bf16x8, vfb0), O[qs * 4 + 0]);
            O[qs * 4 + 1] = MFMA16(pa0, __builtin_bit_cast(bf16x8, vfa1), O[qs * 4 + 1]);
            O[qs * 4 + 1] = MFMA16(pa1, __builtin_bit_cast(bf16x8, vfb1), O[qs * 4 + 1]);
            O[qs * 4 + 2] = MFMA16(pa0, __builtin_bit_cast(bf16x8, vfa2), O[qs * 4 + 2]);
            O[qs * 4 + 2] = MFMA16(pa1, __builtin_bit_cast(bf16x8, vfb2), O[qs * 4 + 2]);
            O[qs * 4 + 3] = MFMA16(pa0, __builtin_bit_cast(bf16x8, vfa3), O[qs * 4 + 3]);
            O[qs * 4 + 3] = MFMA16(pa1, __builtin_bit_cast(bf16x8, vfb3), O[qs * 4 + 3]);
        }
    }

    // ---- row sums -> lc ----
#pragma unroll
    for (int qs = 0; qs < 2; qs++)
#pragma unroll
        for (int j = 0; j < 4; j++) {
            float s = l[qs * 4 + j];
            s += __shfl_xor(s, 1);
            s += __shfl_xor(s, 2);
            s += __shfl_xor(s, 4);
            s += __shfl_xor(s, 8);
            if (lo == 0) lc[w][qs * 16 + hi * 4 + j] = s;
        }
    __syncthreads();    // all Ps reads done; sbuf can be reused as Oc

    // ---- combine tree: waves 0-3 store into Oc[w]; then waves 4-7 add into Oc[w-4] ----
    if (w < 4) {
        float* dst = (float*)(sbuf + w * 8192);
#pragma unroll
        for (int qs = 0; qs < 2; qs++)
#pragma unroll
            for (int cc = 0; cc < 4; cc++)
#pragma unroll
                for (int j = 0; j < 4; j++)
                    dst[(qs * 16 + hi * 4 + j) * 64 + cc * 16 + lo] = O[qs * 4 + cc][j];
    }
    __syncthreads();
    if (w >= 4) {
        float* dst = (float*)(sbuf + (w - 4) * 8192);
#pragma unroll
        for (int qs = 0; qs < 2; qs++)
#pragma unroll
            for (int cc = 0; cc < 4; cc++)
#pragma unroll
                for (int j = 0; j < 4; j++) {
                    float* p = &dst[(qs * 16 + hi * 4 + j) * 64 + cc * 16 + lo];
                    *p = *p + O[qs * 4 + cc][j];
                }
    }
    __syncthreads();

    // ---- combine 4 buffers, normalize -> PA bf16 (swizzled) ----
    if (tid < 256) {
        int row = tid >> 3;                  // 0..31
        int c0 = (tid & 7) * 8;
        float L = lc[0][row] + lc[1][row] + lc[2][row] + lc[3][row] +
                  lc[4][row] + lc[5][row] + lc[6][row] + lc[7][row];
        float inv = 1.f / L;
        const float* O0 = (const float*)(sbuf);
        const float* O1 = (const float*)(sbuf + 8192);
        const float* O2 = (const float*)(sbuf + 16384);
        const float* O3 = (const float*)(sbuf + 24576);
        int base = row * 64 + c0;
        float4 u0, u1;
        u0.x = (O0[base + 0] + O1[base + 0] + O2[base + 0] + O3[base + 0]) * inv;
        u0.y = (O0[base + 1] + O1[base + 1] + O2[base + 1] + O3[base + 1]) * inv;
        u0.z = (O0[base + 2] + O1[base + 2] + O2[base + 2] + O3[base + 2]) * inv;
        u0.w = (O0[base + 3] + O1[base + 3] + O2[base + 3] + O3[base + 3]) * inv;
        u1.x = (O0[base + 4] + O1[base + 4] + O2[base + 4] + O3[base + 4]) * inv;
        u1.y = (O0[base + 5] + O1[base + 5] + O2[base + 5] + O3[base + 5]) * inv;
        u1.z = (O0[base + 6] + O1[base + 6] + O2[base + 6] + O3[base + 6]) * inv;
        u1.w = (O0[base + 7] + O1[base + 7] + O2[base + 7] + O3[base + 7]) * inv;
        *(short8*)((char*)PA + ((row * 128 + c0 * 2) ^ ((row & 7) << 4))) = pack8(u0, u1);
    }
    __syncthreads();

    // ---- epilogue: waves 0,1 -> Wo MFMA (16 rows each) + residual + SE-mean ----
    if (w < 2) {
        int rl = w * 16 + lo;
        int aswz = (rl & 7) << 4;
        bf16x8 a0 = __builtin_bit_cast(bf16x8, *(const short8*)((char*)PA + ((rl * 128 + hi * 16) ^ aswz)));
        bf16x8 a1 = __builtin_bit_cast(bf16x8, *(const short8*)((char*)PA + ((rl * 128 + 64 + hi * 16) ^ aswz)));
        size_t grow0 = (size_t)b * S_ + sq0 + w * 16;
        float colsum[4];
#pragma unroll
        for (int cc = 0; cc < 4; cc++) {
            int o = cc * 16 + lo;
            float4 f0 = *(const float4*)(wo + o * 64 + hi * 8);
            float4 f1 = *(const float4*)(wo + o * 64 + hi * 8 + 4);
            bf16x8 b0 = __builtin_bit_cast(bf16x8, pack8(f0, f1));
            float4 f2 = *(const float4*)(wo + o * 64 + 32 + hi * 8);
            float4 f3 = *(const float4*)(wo + o * 64 + 32 + hi * 8 + 4);
            bf16x8 b1 = __builtin_bit_cast(bf16x8, pack8(f2, f3));
            f32x4 acc = zero4();
            acc = MFMA16(a0, b0, acc);
            acc = MFMA16(a1, b1, acc);
            float cs = 0.f;
#pragma unroll
            for (int j = 0; j < 4; j++) {
                size_t idx = (grow0 + hi * 4 + j) * 64 + o;
                float xn = acc[j] + voxT[idx];
                xattT[idx] = f2bf(xn);
                cs += xn;
            }
            cs += __shfl_xor(cs, 16);
            cs += __shfl_xor(cs, 32);
            colsum[cc] = cs;
        }
        if (hi == 0) {
#pragma unroll
            for (int cc = 0; cc < 4; cc++) atomicAdd(&sem[cc * 16 + lo], colsum[cc]);
        }
    }
    __syncthreads();
    if (tid < 64) atomicAdd(&semean[b * 64 + tid], sem[tid]);
}

// ---------------- K8: SE gate + devoxelize (bf16 gather) + point MLP + MFMA classifier ----------------
__global__ __launch_bounds__(256) void k_point(const float* __restrict__ coords, const float* __restrict__ feats,
                                               const unsigned short* __restrict__ xt, const float* __restrict__ semean,
                                               const float* __restrict__ sw1, const float* __restrict__ sb1,
                                               const float* __restrict__ sw2, const float* __restrict__ sb2,
                                               const float* __restrict__ pw,
                                               const float* __restrict__ pb, const float* __restrict__ w1,
                                               const float* __restrict__ b1, const float* __restrict__ w2,
                                               const float* __restrict__ b2, float* __restrict__ out) {
    __shared__ unsigned short fl[256 * 64];    // 32KB fused bf16, XOR-swizzled rows
    __shared__ float pwl[64 * 6];
    __shared__ float pbl[64];
    __shared__ float b1l[128];
    __shared__ float w2l[3 * 128];
    __shared__ float b2l[3];
    __shared__ float gl[64];
    __shared__ float sml[64];
    __shared__ float hh[8];
    int tid = threadIdx.x;
    int gidx0 = blockIdx.x * 256;
    int b = gidx0 >> 15, n0 = gidx0 & (N_ - 1);
    int n = n0 + tid;
    for (int i = tid; i < 384; i += 256) { pwl[i] = pw[i]; w2l[i] = w2[i]; }
    if (tid < 128) b1l[tid] = b1[tid];
    if (tid < 64) { pbl[tid] = pb[tid]; sml[tid] = semean[b * 64 + tid] * (1.0f / S_); }
    if (tid < 3) b2l[tid] = b2[tid];
    __syncthreads();
    if (tid < 8) {
        float a = sb1[tid];
#pragma unroll
        for (int i = 0; i < 64; i++) a += sw1[tid * 64 + i] * sml[i];
        hh[tid] = fmaxf(a, 0.f);
    }
    __syncthreads();
    if (tid < 64) {
        float g = sb2[tid];
#pragma unroll
        for (int j = 0; j < 8; j++) g += sw2[tid * 8 + j] * hh[j];
        gl[tid] = 1.f / (1.f + __expf(-g));
    }
    __syncthreads();

    const float* cb = coords + (size_t)b * 3 * N_;
    float px = fminf(fmaxf(cb[n] * R_ - 0.5f, 0.f), 15.f);
    float py = fminf(fmaxf(cb[N_ + n] * R_ - 0.5f, 0.f), 15.f);
    float pz = fminf(fmaxf(cb[2 * N_ + n] * R_ - 0.5f, 0.f), 15.f);
    int x0 = (int)floorf(px); float wx = px - x0; int x1 = min(x0 + 1, 15);
    int y0 = (int)floorf(py); float wy = py - y0; int y1 = min(y0 + 1, 15);
    int z0 = (int)floorf(pz); float wz = pz - z0; int z1 = min(z0 + 1, 15);
    float fused[64];
#pragma unroll
    for (int c = 0; c < 64; c++) fused[c] = 0.f;
    const unsigned short* xb = xt + (size_t)b * S_ * 64;
#pragma unroll
    for (int dx = 0; dx < 2; dx++) {
#pragma unroll
        for (int dy = 0; dy < 2; dy++) {
#pragma unroll
            for (int dz = 0; dz < 2; dz++) {
                int xi = dx ? x1 : x0, yi = dy ? y1 : y0, zi = dz ? z1 : z0;
                float wgt = (dx ? wx : 1.f - wx) * (dy ? wy : 1.f - wy) * (dz ? wz : 1.f - wz);
                const short8* g = (const short8*)(xb + (size_t)((xi * 16 + yi) * 16 + zi) * 64);
#pragma unroll
                for (int c8 = 0; c8 < 8; c8++) {
                    short8 gv = g[c8];
#pragma unroll
                    for (int i = 0; i < 8; i++)
                        fused[c8 * 8 + i] += wgt * bf2f((unsigned short)gv[i]);
                }
            }
        }
    }
    float fv[6];
#pragma unroll
    for (int i = 0; i < 6; i++) fv[i] = feats[((size_t)b * 6 + i) * N_ + n];
#pragma unroll
    for (int c = 0; c < 64; c++) {
        float pt = pbl[c];
#pragma unroll
        for (int i = 0; i < 6; i++) pt += pwl[c * 6 + i] * fv[i];
        pt = fmaxf(pt, 0.f);
        fused[c] = fmaxf(fused[c] * gl[c] + pt, 0.f);
    }
#pragma unroll
    for (int ch = 0; ch < 8; ch++) {
        short8 v;
#pragma unroll
        for (int i = 0; i < 8; i++) v[i] = (short)f2bf(fused[ch * 8 + i]);
        int byte = tid * 128 + ch * 16;
        *(short8*)((char*)fl + (byte ^ ((tid & 7) << 4))) = v;
    }
    __syncthreads();

    int wv = tid >> 6, lane = tid & 63;
    int lo = lane & 15, hi = lane >> 4;
    bf16x8 bw[16];
#pragma unroll
    for (int th = 0; th < 8; th++) {
#pragma unroll
        for (int kf = 0; kf < 2; kf++) {
            const float* wr = w1 + (th * 16 + lo) * 64 + kf * 32 + hi * 8;
            bw[th * 2 + kf] = __builtin_bit_cast(bf16x8, pack8(*(const float4*)wr, *(const float4*)(wr + 4)));
        }
    }
#pragma unroll
    for (int g = 0; g < 4; g++) {
        int row = wv * 64 + g * 16 + lo;
        int swz = (row & 7) << 4;
        bf16x8 a0 = __builtin_bit_cast(bf16x8, *(const short8*)((char*)fl + ((row * 128 + hi * 16) ^ swz)));
        bf16x8 a1 = __builtin_bit_cast(bf16x8, *(const short8*)((char*)fl + ((row * 128 + 64 + hi * 16) ^ swz)));
        f32x4 acc[8];
#pragma unroll
        for (int th = 0; th < 8; th++) {
            acc[th] = zero4();
            acc[th] = MFMA16(a0, bw[th * 2], acc[th]);
            acc[th] = MFMA16(a1, bw[th * 2 + 1], acc[th]);
        }
        float s0[4] = {0.f, 0.f, 0.f, 0.f};
        float s1[4] = {0.f, 0.f, 0.f, 0.f};
        float s2[4] = {0.f, 0.f, 0.f, 0.f};
#pragma unroll
        for (int th = 0; th < 8; th++) {
            int hidx = th * 16 + lo;
            float w2o0 = w2l[hidx];
            float w2o1 = w2l[128 + hidx];
            float w2o2 = w2l[256 + hidx];
            float bias = b1l[hidx];
#pragma unroll
            for (int j = 0; j < 4; j++) {
                float hj = fmaxf(acc[th][j] + bias, 0.f);
                s0[j] += hj * w2o0;
                s1[j] += hj * w2o1;
                s2[j] += hj * w2o2;
            }
        }
#pragma unroll
        for (int j = 0; j < 4; j++) {
            s0[j] += __shfl_xor(s0[j], 1); s0[j] += __shfl_xor(s0[j], 2);
            s0[j] += __shfl_xor(s0[j], 4); s0[j] += __shfl_xor(s0[j], 8);
            s1[j] += __shfl_xor(s1[j], 1); s1[j] += __shfl_xor(s1[j], 2);
            s1[j] += __shfl_xor(s1[j], 4); s1[j] += __shfl_xor(s1[j], 8);
            s2[j] += __shfl_xor(s2[j], 1); s2[j] += __shfl_xor(s2[j], 2);
            s2[j] += __shfl_xor(s2[j], 4); s2[j] += __shfl_xor(s2[j], 8);
        }
        int nbase = n0 + wv * 64 + g * 16 + hi * 4;
        if (lo == 0) {
            float4 o4 = make_float4(s0[0] + b2l[0], s0[1] + b2l[0], s0[2] + b2l[0], s0[3] + b2l[0]);
            *(float4*)(out + ((size_t)b * 3 + 0) * N_ + nbase) = o4;
        } else if (lo == 1) {
            float4 o4 = make_float4(s1[0] + b2l[1], s1[1] + b2l[1], s1[2] + b2l[1], s1[3] + b2l[1]);
            *(float4*)(out + ((size_t)b * 3 + 1) * N_ + nbase) = o4;
        } else if (lo == 2) {
            float4 o4 = make_float4(s2[0] + b2l[2], s2[1] + b2l[2], s2[2] + b2l[2], s2[3] + b2l[2]);
            *(float4*)(out + ((size_t)b * 3 + 2) * N_ + nbase) = o4;
        }
    }
}

extern "C" void kernel_launch(void* const* d_in, const int* in_sizes, int n_in,
                              void* d_out, int out_size, void* d_ws, size_t ws_size,
                              hipStream_t stream) {
    const float* coords  = (const float*)d_in[0];
    const float* feats   = (const float*)d_in[1];
    const float* conv_w  = (const float*)d_in[2];
    const float* conv_b  = (const float*)d_in[3];
    const float* wq      = (const float*)d_in[4];
    const float* wk      = (const float*)d_in[5];
    const float* wv      = (const float*)d_in[6];
    const float* wo      = (const float*)d_in[7];
    const float* se_w1   = (const float*)d_in[8];
    const float* se_b1   = (const float*)d_in[9];
    const float* se_w2   = (const float*)d_in[10];
    const float* se_b2   = (const float*)d_in[11];
    const float* point_w = (const float*)d_in[12];
    const float* point_b = (const float*)d_in[13];
    const float* cls_w1  = (const float*)d_in[14];
    const float* cls_b1  = (const float*)d_in[15];
    const float* cls_w2  = (const float*)d_in[16];
    const float* cls_b2  = (const float*)d_in[17];

    float* ws = (float*)d_ws;
    float* vsum   = ws;                        // 98304
    float* cnt    = ws + 98304;                // 16384
    float* semean = ws + 114688;               // 256
    float* vox    = ws + 115200;               // 1048576 [conv2 -> qkv3]; reused as xattT (bf16)
    float* voxT   = vox + 1048576;             // 1048576 [qkv3 -> attn epilogue residual]
    unsigned short* qT = (unsigned short*)(voxT + 1048576);
    unsigned short* kT = qT + 1048576;
    unsigned short* vT = kT + 1048576;
    unsigned short* xattT = (unsigned short*)vox;   // bf16 [b][s][64]; vox dead after qkv3

    hipMemsetAsync(ws, 0, 114944 * sizeof(float), stream);    // vsum + cnt + semean
    k_voxelize<<<512, 256, 0, stream>>>(coords, feats, vsum, cnt);
    k_conv2<<<512, 256, 0, stream>>>(vsum, cnt, conv_w, conv_b, vox);
    k_qkv3<<<512, 256, 0, stream>>>(vox, wq, wk, wv, qT, kT, vT, voxT);
    k_attn10<<<512, 512, 0, stream>>>(qT, kT, vT, wo, voxT, xattT, semean);
    k_point<<<512, 256, 0, stream>>>(coords, feats, xattT, semean,
                                     se_w1, se_b1, se_w2, se_b2, point_w, point_b,
                                     cls_w1, cls_b1, cls_w2, cls_b2, (float*)d_out);
}

// Round 15
// 202.844 us; speedup vs baseline: 1.3870x; 1.1239x over previous
//
#include <hip/hip_runtime.h>
#include <hip/hip_bf16.h>
#include <math.h>

#define B_ 4
#define N_ 32768
#define CIN 6
#define C_ 64
#define R_ 16
#define S_ 4096

typedef __attribute__((ext_vector_type(8))) __bf16 bf16x8;
typedef __attribute__((ext_vector_type(8))) short short8;
typedef __attribute__((ext_vector_type(4))) short s16x4;
typedef __attribute__((ext_vector_type(4))) float f32x4;

#define MFMA16(a, b, c) __builtin_amdgcn_mfma_f32_16x16x32_bf16((a), (b), (c), 0, 0, 0)

__device__ inline f32x4 zero4() {
    f32x4 z;
    z[0] = 0.f; z[1] = 0.f; z[2] = 0.f; z[3] = 0.f;
    return z;
}

__device__ inline unsigned short f2bf(float f) {
    unsigned u = __builtin_bit_cast(unsigned, f);
    u += 0x7fffu + ((u >> 16) & 1u);          // RNE
    return (unsigned short)(u >> 16);
}

__device__ inline float bf2f(unsigned short s) {
    unsigned u = ((unsigned)s) << 16;
    return __builtin_bit_cast(float, u);
}

__device__ inline short8 pack8(float4 a, float4 b) {
    short8 r;
    r[0] = (short)f2bf(a.x); r[1] = (short)f2bf(a.y); r[2] = (short)f2bf(a.z); r[3] = (short)f2bf(a.w);
    r[4] = (short)f2bf(b.x); r[5] = (short)f2bf(b.y); r[6] = (short)f2bf(b.z); r[7] = (short)f2bf(b.w);
    return r;
}

__device__ inline bf16x8 pack8b(float4 a, float4 b) {
    return __builtin_bit_cast(bf16x8, pack8(a, b));
}

// ---------------- K1: voxelize scatter-add ----------------
__global__ void k_voxelize(const float* __restrict__ coords, const float* __restrict__ feats,
                           float* __restrict__ vsum, float* __restrict__ cnt) {
    int idx = blockIdx.x * 256 + threadIdx.x;
    int b = idx >> 15, n = idx & (N_ - 1);
    const float* cb = coords + (size_t)b * 3 * N_;
    float x = cb[n], y = cb[N_ + n], z = cb[2 * N_ + n];
    int vx = min(max((int)floorf(x * R_), 0), R_ - 1);
    int vy = min(max((int)floorf(y * R_), 0), R_ - 1);
    int vz = min(max((int)floorf(z * R_), 0), R_ - 1);
    int cell = (vx * R_ + vy) * R_ + vz;
    float* vs = vsum + (size_t)b * CIN * S_;
    const float* fb = feats + (size_t)b * CIN * N_;
#pragma unroll
    for (int f = 0; f < CIN; f++) atomicAdd(&vs[f * S_ + cell], fb[f * N_ + n]);
    atomicAdd(&cnt[b * S_ + cell], 1.0f);
}

// ---------------- K2: conv + fused mean-division -> voxT f32 [b][s][64] ----------------
__global__ __launch_bounds__(256) void k_conv2(const float* __restrict__ vsum, const float* __restrict__ cnt,
                                               const float* __restrict__ w, const float* __restrict__ bias,
                                               float* __restrict__ voxT) {
    __shared__ float msl[3][CIN][256];
    __shared__ float wl[8 * 162];
    int bid = blockIdx.x;                 // b(4) x x(16) x og(8) = 512
    int b = bid >> 7;
    int x = (bid >> 3) & 15;
    int o0 = (bid & 7) * 8;
    int tid = threadIdx.x;
    for (int i = tid; i < 8 * 162; i += 256) wl[i] = w[o0 * 162 + i];
#pragma unroll
    for (int sl = 0; sl < 3; sl++) {
        int xx = x - 1 + sl;
        if (xx >= 0 && xx < 16) {
            float c = cnt[b * S_ + xx * 256 + tid];
            float invc = 1.f / fmaxf(c, 1.f);
#pragma unroll
            for (int i = 0; i < CIN; i++)
                msl[sl][i][tid] = vsum[((size_t)b * CIN + i) * S_ + xx * 256 + tid] * invc;
        } else {
#pragma unroll
            for (int i = 0; i < CIN; i++) msl[sl][i][tid] = 0.f;
        }
    }
    __syncthreads();
    int y = tid >> 4, z = tid & 15;
    float acc[8];
#pragma unroll
    for (int oj = 0; oj < 8; oj++) acc[oj] = bias[o0 + oj];
#pragma unroll
    for (int dx = 0; dx < 3; dx++) {
#pragma unroll
        for (int dy = 0; dy < 3; dy++) {
            int yy = y + dy - 1;
            if ((unsigned)yy >= 16u) continue;
#pragma unroll
            for (int dz = 0; dz < 3; dz++) {
                int zz = z + dz - 1;
                if ((unsigned)zz >= 16u) continue;
                int idx = yy * 16 + zz;
#pragma unroll
                for (int i = 0; i < CIN; i++) {
                    float m = msl[dx][i][idx];
                    int wb = i * 27 + dx * 9 + dy * 3 + dz;
#pragma unroll
                    for (int oj = 0; oj < 8; oj++) acc[oj] += wl[oj * 162 + wb] * m;
                }
            }
        }
    }
    int cell = x * 256 + tid;
    float* dst = voxT + ((size_t)b * S_ + cell) * 64 + o0;
    *(float4*)dst = make_float4(fmaxf(acc[0], 0.f), fmaxf(acc[1], 0.f), fmaxf(acc[2], 0.f), fmaxf(acc[3], 0.f));
    *(float4*)(dst + 4) = make_float4(fmaxf(acc[4], 0.f), fmaxf(acc[5], 0.f), fmaxf(acc[6], 0.f), fmaxf(acc[7], 0.f));
}

// ---------------- K3: qkv via MFMA: [16384x64] x [64x192] -> qT,kT [s][64]; vT [c][t] ----------------
__global__ __launch_bounds__(256) void k_qkv4(const float* __restrict__ voxT,
                                              const float* __restrict__ wq, const float* __restrict__ wk,
                                              const float* __restrict__ wv,
                                              unsigned short* __restrict__ qT, unsigned short* __restrict__ kT,
                                              unsigned short* __restrict__ vT) {
    int bid = blockIdx.x;                 // 256: b(4) x chunk(64)
    int b = bid >> 6;
    int srow = (bid & 63) * 64 + (threadIdx.x >> 6) * 16;   // 16 rows per wave
    int lane = threadIdx.x & 63;
    int lo = lane & 15, hi = lane >> 4;

    // A-frags: x rows f32 -> bf16
    const float* xr = voxT + ((size_t)b * S_ + srow + lo) * 64 + hi * 8;
    bf16x8 a0 = pack8b(*(const float4*)xr, *(const float4*)(xr + 4));
    bf16x8 a1 = pack8b(*(const float4*)(xr + 32), *(const float4*)(xr + 36));

#pragma unroll
    for (int m = 0; m < 3; m++) {
        const float* wp = (m == 0) ? wq : (m == 1) ? wk : wv;
#pragma unroll
        for (int oc = 0; oc < 4; oc++) {
            const float* wr = wp + (oc * 16 + lo) * 64 + hi * 8;
            bf16x8 b0 = pack8b(*(const float4*)wr, *(const float4*)(wr + 4));
            bf16x8 b1 = pack8b(*(const float4*)(wr + 32), *(const float4*)(wr + 36));
            f32x4 acc = zero4();
            acc = MFMA16(a0, b0, acc);
            acc = MFMA16(a1, b1, acc);
            if (m < 2) {
                unsigned short* dst = ((m == 0) ? qT : kT) + ((size_t)b * S_ + srow + hi * 4) * 64 + oc * 16 + lo;
#pragma unroll
                for (int j = 0; j < 4; j++) dst[(size_t)j * 64] = f2bf(acc[j]);
            } else {
                s16x4 pk;
#pragma unroll
                for (int j = 0; j < 4; j++) pk[j] = (short)f2bf(acc[j]);
                *(s16x4*)(vT + ((size_t)b * 64 + oc * 16 + lo) * S_ + srow + hi * 4) = pk;
            }
        }
    }
}

// ---------------- K4: attn6 core + fused Wo/residual/SE epilogue -> xattT bf16 (R10 proven) ----------------
__global__ __launch_bounds__(256, 2) void k_attn9(const unsigned short* __restrict__ qT,
                                                  const unsigned short* __restrict__ kT,
                                                  const unsigned short* __restrict__ vT,
                                                  const float* __restrict__ wo,
                                                  const float* __restrict__ voxT,
                                                  unsigned short* __restrict__ xattT,
                                                  float* __restrict__ semean) {
    __shared__ unsigned short Ps[4][2048];     // 16KB; Ps[0] reused as PA (4KB) post-loop
    __shared__ float Oc[4][2048];              // 32KB combine buffers
    __shared__ float lc[4][32];
    __shared__ float sem[64];
    int bid = blockIdx.x;                      // 512: b(4) x qtile(128)
    int b = bid >> 7;
    int sq0 = (bid & 127) * 32;
    int tid = threadIdx.x;
    int w = tid >> 6, lane = tid & 63;
    int lo = lane & 15, hi = lane >> 4;
    if (tid < 64) sem[tid] = 0.f;

    const unsigned short* qb = qT + ((size_t)b * S_ + sq0) * 64;
    bf16x8 qf00 = __builtin_bit_cast(bf16x8, *(const short8*)(qb + lo * 64 + hi * 8));
    bf16x8 qf01 = __builtin_bit_cast(bf16x8, *(const short8*)(qb + lo * 64 + hi * 8 + 32));
    bf16x8 qf10 = __builtin_bit_cast(bf16x8, *(const short8*)(qb + (16 + lo) * 64 + hi * 8));
    bf16x8 qf11 = __builtin_bit_cast(bf16x8, *(const short8*)(qb + (16 + lo) * 64 + hi * 8 + 32));

    f32x4 O[8];
    float l[8];
#pragma unroll
    for (int i = 0; i < 8; i++) O[i] = zero4();
#pragma unroll
    for (int i = 0; i < 8; i++) l[i] = 0.f;

    const unsigned short* kb = kT + (size_t)b * S_ * 64 + hi * 8;
    const unsigned short* vb = vT + (size_t)b * 64 * S_;

    for (int t0 = w * 1024; t0 < w * 1024 + 1024; t0 += 64) {
        short8 vfa0, vfb0, vfa1, vfb1, vfa2, vfb2, vfa3, vfb3;
        {
            const unsigned short* vr0 = vb + (size_t)(0 + lo) * S_ + t0 + hi * 8;
            const unsigned short* vr1 = vb + (size_t)(16 + lo) * S_ + t0 + hi * 8;
            const unsigned short* vr2 = vb + (size_t)(32 + lo) * S_ + t0 + hi * 8;
            const unsigned short* vr3 = vb + (size_t)(48 + lo) * S_ + t0 + hi * 8;
            vfa0 = *(const short8*)vr0; vfb0 = *(const short8*)(vr0 + 32);
            vfa1 = *(const short8*)vr1; vfb1 = *(const short8*)(vr1 + 32);
            vfa2 = *(const short8*)vr2; vfb2 = *(const short8*)(vr2 + 32);
            vfa3 = *(const short8*)vr3; vfb3 = *(const short8*)(vr3 + 32);
        }
#pragma unroll
        for (int ct = 0; ct < 4; ct++) {
            const unsigned short* kr = kb + (size_t)(t0 + ct * 16 + lo) * 64;
            bf16x8 kf0 = __builtin_bit_cast(bf16x8, *(const short8*)kr);
            bf16x8 kf1 = __builtin_bit_cast(bf16x8, *(const short8*)(kr + 32));
#pragma unroll
            for (int qs = 0; qs < 2; qs++) {
                f32x4 z = zero4();
                z = MFMA16(qs ? qf10 : qf00, kf0, z);
                f32x4 Sacc = MFMA16(qs ? qf11 : qf01, kf1, z);
#pragma unroll
                for (int j = 0; j < 4; j++) {
                    float p = __expf(Sacc[j] * 0.125f);
                    l[qs * 4 + j] += p;
                    int r = qs * 16 + hi * 4 + j;
                    int swz = (r & 7) << 4;
                    *(unsigned short*)((char*)&Ps[w][0] + ((r * 128 + (ct * 16 + lo) * 2) ^ swz)) = f2bf(p);
                }
            }
        }
#pragma unroll
        for (int qs = 0; qs < 2; qs++) {
            int row = qs * 16 + lo;
            int swz2 = (row & 7) << 4;
            bf16x8 pa0 = __builtin_bit_cast(bf16x8, *(const short8*)((char*)&Ps[w][0] + ((row * 128 + hi * 16) ^ swz2)));
            bf16x8 pa1 = __builtin_bit_cast(bf16x8, *(const short8*)((char*)&Ps[w][0] + ((row * 128 + 64 + hi * 16) ^ swz2)));
            O[qs * 4 + 0] = MFMA16(pa0, __builtin_bit_cast(bf16x8, vfa0), O[qs * 4 + 0]);
            O[qs * 4 + 0] = MFMA16(pa1, __builtin_bit_cast(bf16x8, vfb0), O[qs * 4 + 0]);
            O[qs * 4 + 1] = MFMA16(pa0, __builtin_bit_cast(bf16x8, vfa1), O[qs * 4 + 1]);
            O[qs * 4 + 1] = MFMA16(pa1, __builtin_bit_cast(bf16x8, vfb1), O[qs * 4 + 1]);
            O[qs * 4 + 2] = MFMA16(pa0, __builtin_bit_cast(bf16x8, vfa2), O[qs * 4 + 2]);
            O[qs * 4 + 2] = MFMA16(pa1, __builtin_bit_cast(bf16x8, vfb2), O[qs * 4 + 2]);
            O[qs * 4 + 3] = MFMA16(pa0, __builtin_bit_cast(bf16x8, vfa3), O[qs * 4 + 3]);
            O[qs * 4 + 3] = MFMA16(pa1, __builtin_bit_cast(bf16x8, vfb3), O[qs * 4 + 3]);
        }
    }

#pragma unroll
    for (int qs = 0; qs < 2; qs++)
#pragma unroll
        for (int cc = 0; cc < 4; cc++)
#pragma unroll
            for (int j = 0; j < 4; j++)
                Oc[w][(qs * 16 + hi * 4 + j) * 64 + cc * 16 + lo] = O[qs * 4 + cc][j];
#pragma unroll
    for (int qs = 0; qs < 2; qs++)
#pragma unroll
        for (int j = 0; j < 4; j++) {
            float s = l[qs * 4 + j];
            s += __shfl_xor(s, 1);
            s += __shfl_xor(s, 2);
            s += __shfl_xor(s, 4);
            s += __shfl_xor(s, 8);
            if (lo == 0) lc[w][qs * 16 + hi * 4 + j] = s;
        }
    __syncthreads();

    unsigned short* PA = &Ps[0][0];
    {
        int row = tid >> 3;
        int c0 = (tid & 7) * 8;
        float L = lc[0][row] + lc[1][row] + lc[2][row] + lc[3][row];
        float inv = 1.f / L;
        int base = row * 64 + c0;
        float4 u0, u1;
        u0.x = (Oc[0][base + 0] + Oc[1][base + 0] + Oc[2][base + 0] + Oc[3][base + 0]) * inv;
        u0.y = (Oc[0][base + 1] + Oc[1][base + 1] + Oc[2][base + 1] + Oc[3][base + 1]) * inv;
        u0.z = (Oc[0][base + 2] + Oc[1][base + 2] + Oc[2][base + 2] + Oc[3][base + 2]) * inv;
        u0.w = (Oc[0][base + 3] + Oc[1][base + 3] + Oc[2][base + 3] + Oc[3][base + 3]) * inv;
        u1.x = (Oc[0][base + 4] + Oc[1][base + 4] + Oc[2][base + 4] + Oc[3][base + 4]) * inv;
        u1.y = (Oc[0][base + 5] + Oc[1][base + 5] + Oc[2][base + 5] + Oc[3][base + 5]) * inv;
        u1.z = (Oc[0][base + 6] + Oc[1][base + 6] + Oc[2][base + 6] + Oc[3][base + 6]) * inv;
        u1.w = (Oc[0][base + 7] + Oc[1][base + 7] + Oc[2][base + 7] + Oc[3][base + 7]) * inv;
        *(short8*)((char*)PA + ((row * 128 + c0 * 2) ^ ((row & 7) << 4))) = pack8(u0, u1);
    }
    __syncthreads();

    if (w < 2) {
        int rl = w * 16 + lo;
        int aswz = (rl & 7) << 4;
        bf16x8 a0 = __builtin_bit_cast(bf16x8, *(const short8*)((char*)PA + ((rl * 128 + hi * 16) ^ aswz)));
        bf16x8 a1 = __builtin_bit_cast(bf16x8, *(const short8*)((char*)PA + ((rl * 128 + 64 + hi * 16) ^ aswz)));
        size_t grow0 = (size_t)b * S_ + sq0 + w * 16;
        float colsum[4];
#pragma unroll
        for (int cc = 0; cc < 4; cc++) {
            int o = cc * 16 + lo;
            float4 f0 = *(const float4*)(wo + o * 64 + hi * 8);
            float4 f1 = *(const float4*)(wo + o * 64 + hi * 8 + 4);
            bf16x8 b0 = pack8b(f0, f1);
            float4 f2 = *(const float4*)(wo + o * 64 + 32 + hi * 8);
            float4 f3 = *(const float4*)(wo + o * 64 + 32 + hi * 8 + 4);
            bf16x8 b1 = pack8b(f2, f3);
            f32x4 acc = zero4();
            acc = MFMA16(a0, b0, acc);
            acc = MFMA16(a1, b1, acc);
            float cs = 0.f;
#pragma unroll
            for (int j = 0; j < 4; j++) {
                size_t idx = (grow0 + hi * 4 + j) * 64 + o;
                float xn = acc[j] + voxT[idx];
                xattT[idx] = f2bf(xn);
                cs += xn;
            }
            cs += __shfl_xor(cs, 16);
            cs += __shfl_xor(cs, 32);
            colsum[cc] = cs;
        }
        if (hi == 0) {
#pragma unroll
            for (int cc = 0; cc < 4; cc++) atomicAdd(&sem[cc * 16 + lo], colsum[cc]);
        }
    }
    __syncthreads();
    if (tid < 64) atomicAdd(&semean[b * 64 + tid], sem[tid]);
}

// ---------------- K8: SE gate + devoxelize (bf16 gather) + point MLP + MFMA classifier ----------------
__global__ __launch_bounds__(256) void k_point(const float* __restrict__ coords, const float* __restrict__ feats,
                                               const unsigned short* __restrict__ xt, const float* __restrict__ semean,
                                               const float* __restrict__ sw1, const float* __restrict__ sb1,
                                               const float* __restrict__ sw2, const float* __restrict__ sb2,
                                               const float* __restrict__ pw,
                                               const float* __restrict__ pb, const float* __restrict__ w1,
                                               const float* __restrict__ b1, const float* __restrict__ w2,
                                               const float* __restrict__ b2, float* __restrict__ out) {
    __shared__ unsigned short fl[256 * 64];    // 32KB fused bf16, XOR-swizzled rows
    __shared__ float pwl[64 * 6];
    __shared__ float pbl[64];
    __shared__ float b1l[128];
    __shared__ float w2l[3 * 128];
    __shared__ float b2l[3];
    __shared__ float gl[64];
    __shared__ float sml[64];
    __shared__ float hh[8];
    int tid = threadIdx.x;
    int gidx0 = blockIdx.x * 256;
    int b = gidx0 >> 15, n0 = gidx0 & (N_ - 1);
    int n = n0 + tid;
    for (int i = tid; i < 384; i += 256) { pwl[i] = pw[i]; w2l[i] = w2[i]; }
    if (tid < 128) b1l[tid] = b1[tid];
    if (tid < 64) { pbl[tid] = pb[tid]; sml[tid] = semean[b * 64 + tid] * (1.0f / S_); }
    if (tid < 3) b2l[tid] = b2[tid];
    __syncthreads();
    if (tid < 8) {
        float a = sb1[tid];
#pragma unroll
        for (int i = 0; i < 64; i++) a += sw1[tid * 64 + i] * sml[i];
        hh[tid] = fmaxf(a, 0.f);
    }
    __syncthreads();
    if (tid < 64) {
        float g = sb2[tid];
#pragma unroll
        for (int j = 0; j < 8; j++) g += sw2[tid * 8 + j] * hh[j];
        gl[tid] = 1.f / (1.f + __expf(-g));
    }
    __syncthreads();

    const float* cb = coords + (size_t)b * 3 * N_;
    float px = fminf(fmaxf(cb[n] * R_ - 0.5f, 0.f), 15.f);
    float py = fminf(fmaxf(cb[N_ + n] * R_ - 0.5f, 0.f), 15.f);
    float pz = fminf(fmaxf(cb[2 * N_ + n] * R_ - 0.5f, 0.f), 15.f);
    int x0 = (int)floorf(px); float wx = px - x0; int x1 = min(x0 + 1, 15);
    int y0 = (int)floorf(py); float wy = py - y0; int y1 = min(y0 + 1, 15);
    int z0 = (int)floorf(pz); float wz = pz - z0; int z1 = min(z0 + 1, 15);
    float fused[64];
#pragma unroll
    for (int c = 0; c < 64; c++) fused[c] = 0.f;
    const unsigned short* xb = xt + (size_t)b * S_ * 64;
#pragma unroll
    for (int dx = 0; dx < 2; dx++) {
#pragma unroll
        for (int dy = 0; dy < 2; dy++) {
#pragma unroll
            for (int dz = 0; dz < 2; dz++) {
                int xi = dx ? x1 : x0, yi = dy ? y1 : y0, zi = dz ? z1 : z0;
                float wgt = (dx ? wx : 1.f - wx) * (dy ? wy : 1.f - wy) * (dz ? wz : 1.f - wz);
                const short8* g = (const short8*)(xb + (size_t)((xi * 16 + yi) * 16 + zi) * 64);
#pragma unroll
                for (int c8 = 0; c8 < 8; c8++) {
                    short8 gv = g[c8];
#pragma unroll
                    for (int i = 0; i < 8; i++)
                        fused[c8 * 8 + i] += wgt * bf2f((unsigned short)gv[i]);
                }
            }
        }
    }
    float fv[6];
#pragma unroll
    for (int i = 0; i < 6; i++) fv[i] = feats[((size_t)b * 6 + i) * N_ + n];
#pragma unroll
    for (int c = 0; c < 64; c++) {
        float pt = pbl[c];
#pragma unroll
        for (int i = 0; i < 6; i++) pt += pwl[c * 6 + i] * fv[i];
        pt = fmaxf(pt, 0.f);
        fused[c] = fmaxf(fused[c] * gl[c] + pt, 0.f);
    }
#pragma unroll
    for (int ch = 0; ch < 8; ch++) {
        short8 v;
#pragma unroll
        for (int i = 0; i < 8; i++) v[i] = (short)f2bf(fused[ch * 8 + i]);
        int byte = tid * 128 + ch * 16;
        *(short8*)((char*)fl + (byte ^ ((tid & 7) << 4))) = v;
    }
    __syncthreads();

    int wv = tid >> 6, lane = tid & 63;
    int lo = lane & 15, hi = lane >> 4;
    bf16x8 bw[16];
#pragma unroll
    for (int th = 0; th < 8; th++) {
#pragma unroll
        for (int kf = 0; kf < 2; kf++) {
            const float* wr = w1 + (th * 16 + lo) * 64 + kf * 32 + hi * 8;
            bw[th * 2 + kf] = pack8b(*(const float4*)wr, *(const float4*)(wr + 4));
        }
    }
#pragma unroll
    for (int g = 0; g < 4; g++) {
        int row = wv * 64 + g * 16 + lo;
        int swz = (row & 7) << 4;
        bf16x8 a0 = __builtin_bit_cast(bf16x8, *(const short8*)((char*)fl + ((row * 128 + hi * 16) ^ swz)));
        bf16x8 a1 = __builtin_bit_cast(bf16x8, *(const short8*)((char*)fl + ((row * 128 + 64 + hi * 16) ^ swz)));
        f32x4 acc[8];
#pragma unroll
        for (int th = 0; th < 8; th++) {
            acc[th] = zero4();
            acc[th] = MFMA16(a0, bw[th * 2], acc[th]);
            acc[th] = MFMA16(a1, bw[th * 2 + 1], acc[th]);
        }
        float s0[4] = {0.f, 0.f, 0.f, 0.f};
        float s1[4] = {0.f, 0.f, 0.f, 0.f};
        float s2[4] = {0.f, 0.f, 0.f, 0.f};
#pragma unroll
        for (int th = 0; th < 8; th++) {
            int hidx = th * 16 + lo;
            float w2o0 = w2l[hidx];
            float w2o1 = w2l[128 + hidx];
            float w2o2 = w2l[256 + hidx];
            float bias = b1l[hidx];
#pragma unroll
            for (int j = 0; j < 4; j++) {
                float hj = fmaxf(acc[th][j] + bias, 0.f);
                s0[j] += hj * w2o0;
                s1[j] += hj * w2o1;
                s2[j] += hj * w2o2;
            }
        }
#pragma unroll
        for (int j = 0; j < 4; j++) {
            s0[j] += __shfl_xor(s0[j], 1); s0[j] += __shfl_xor(s0[j], 2);
            s0[j] += __shfl_xor(s0[j], 4); s0[j] += __shfl_xor(s0[j], 8);
            s1[j] += __shfl_xor(s1[j], 1); s1[j] += __shfl_xor(s1[j], 2);
            s1[j] += __shfl_xor(s1[j], 4); s1[j] += __shfl_xor(s1[j], 8);
            s2[j] += __shfl_xor(s2[j], 1); s2[j] += __shfl_xor(s2[j], 2);
            s2[j] += __shfl_xor(s2[j], 4); s2[j] += __shfl_xor(s2[j], 8);
        }
        int nbase = n0 + wv * 64 + g * 16 + hi * 4;
        if (lo == 0) {
            float4 o4 = make_float4(s0[0] + b2l[0], s0[1] + b2l[0], s0[2] + b2l[0], s0[3] + b2l[0]);
            *(float4*)(out + ((size_t)b * 3 + 0) * N_ + nbase) = o4;
        } else if (lo == 1) {
            float4 o4 = make_float4(s1[0] + b2l[1], s1[1] + b2l[1], s1[2] + b2l[1], s1[3] + b2l[1]);
            *(float4*)(out + ((size_t)b * 3 + 1) * N_ + nbase) = o4;
        } else if (lo == 2) {
            float4 o4 = make_float4(s2[0] + b2l[2], s2[1] + b2l[2], s2[2] + b2l[2], s2[3] + b2l[2]);
            *(float4*)(out + ((size_t)b * 3 + 2) * N_ + nbase) = o4;
        }
    }
}

extern "C" void kernel_launch(void* const* d_in, const int* in_sizes, int n_in,
                              void* d_out, int out_size, void* d_ws, size_t ws_size,
                              hipStream_t stream) {
    const float* coords  = (const float*)d_in[0];
    const float* feats   = (const float*)d_in[1];
    const float* conv_w  = (const float*)d_in[2];
    const float* conv_b  = (const float*)d_in[3];
    const float* wq      = (const float*)d_in[4];
    const float* wk      = (const float*)d_in[5];
    const float* wv      = (const float*)d_in[6];
    const float* wo      = (const float*)d_in[7];
    const float* se_w1   = (const float*)d_in[8];
    const float* se_b1   = (const float*)d_in[9];
    const float* se_w2   = (const float*)d_in[10];
    const float* se_b2   = (const float*)d_in[11];
    const float* point_w = (const float*)d_in[12];
    const float* point_b = (const float*)d_in[13];
    const float* cls_w1  = (const float*)d_in[14];
    const float* cls_b1  = (const float*)d_in[15];
    const float* cls_w2  = (const float*)d_in[16];
    const float* cls_b2  = (const float*)d_in[17];

    float* ws = (float*)d_ws;
    float* vsum   = ws;                        // 98304
    float* cnt    = ws + 98304;                // 16384
    float* semean = ws + 114688;               // 256
    float* vox    = ws + 115200;               // region reused as xattT (bf16)
    float* voxT   = vox + 1048576;             // f32 [b][s][64]: conv2 -> qkv4 + attn residual
    unsigned short* qT = (unsigned short*)(voxT + 1048576);
    unsigned short* kT = qT + 1048576;
    unsigned short* vT = kT + 1048576;
    unsigned short* xattT = (unsigned short*)vox;   // bf16 [b][s][64]

    hipMemsetAsync(ws, 0, 114944 * sizeof(float), stream);    // vsum + cnt + semean
    k_voxelize<<<512, 256, 0, stream>>>(coords, feats, vsum, cnt);
    k_conv2<<<512, 256, 0, stream>>>(vsum, cnt, conv_w, conv_b, voxT);
    k_qkv4<<<256, 256, 0, stream>>>(voxT, wq, wk, wv, qT, kT, vT);
    k_attn9<<<512, 256, 0, stream>>>(qT, kT, vT, wo, voxT, xattT, semean);
    k_point<<<512, 256, 0, stream>>>(coords, feats, xattT, semean,
                                     se_w1, se_b1, se_w2, se_b2, point_w, point_b,
                                     cls_w1, cls_b1, cls_w2, cls_b2, (float*)d_out);
}

// Round 16
// 184.538 us; speedup vs baseline: 1.5246x; 1.0992x over previous
//
#include <hip/hip_runtime.h>
#include <hip/hip_bf16.h>
#include <math.h>

#define B_ 4
#define N_ 32768
#define CIN 6
#define C_ 64
#define R_ 16
#define S_ 4096

typedef __attribute__((ext_vector_type(8))) __bf16 bf16x8;
typedef __attribute__((ext_vector_type(8))) short short8;
typedef __attribute__((ext_vector_type(4))) short s16x4;
typedef __attribute__((ext_vector_type(4))) float f32x4;

#define MFMA16(a, b, c) __builtin_amdgcn_mfma_f32_16x16x32_bf16((a), (b), (c), 0, 0, 0)

__device__ inline f32x4 zero4() {
    f32x4 z;
    z[0] = 0.f; z[1] = 0.f; z[2] = 0.f; z[3] = 0.f;
    return z;
}

__device__ inline unsigned short f2bf(float f) {
    unsigned u = __builtin_bit_cast(unsigned, f);
    u += 0x7fffu + ((u >> 16) & 1u);          // RNE
    return (unsigned short)(u >> 16);
}

__device__ inline float bf2f(unsigned short s) {
    unsigned u = ((unsigned)s) << 16;
    return __builtin_bit_cast(float, u);
}

__device__ inline short8 pack8(float4 a, float4 b) {
    short8 r;
    r[0] = (short)f2bf(a.x); r[1] = (short)f2bf(a.y); r[2] = (short)f2bf(a.z); r[3] = (short)f2bf(a.w);
    r[4] = (short)f2bf(b.x); r[5] = (short)f2bf(b.y); r[6] = (short)f2bf(b.z); r[7] = (short)f2bf(b.w);
    return r;
}

__device__ inline bf16x8 pack8b(float4 a, float4 b) {
    return __builtin_bit_cast(bf16x8, pack8(a, b));
}

// ---------------- K1: voxelize scatter-add ----------------
__global__ void k_voxelize(const float* __restrict__ coords, const float* __restrict__ feats,
                           float* __restrict__ vsum, float* __restrict__ cnt) {
    int idx = blockIdx.x * 256 + threadIdx.x;
    int b = idx >> 15, n = idx & (N_ - 1);
    const float* cb = coords + (size_t)b * 3 * N_;
    float x = cb[n], y = cb[N_ + n], z = cb[2 * N_ + n];
    int vx = min(max((int)floorf(x * R_), 0), R_ - 1);
    int vy = min(max((int)floorf(y * R_), 0), R_ - 1);
    int vz = min(max((int)floorf(z * R_), 0), R_ - 1);
    int cell = (vx * R_ + vy) * R_ + vz;
    float* vs = vsum + (size_t)b * CIN * S_;
    const float* fb = feats + (size_t)b * CIN * N_;
#pragma unroll
    for (int f = 0; f < CIN; f++) atomicAdd(&vs[f * S_ + cell], fb[f * N_ + n]);
    atomicAdd(&cnt[b * S_ + cell], 1.0f);
}

// ---------------- K2: conv + fused mean-division -> voxT f32 [b][s][64] ----------------
__global__ __launch_bounds__(256) void k_conv2(const float* __restrict__ vsum, const float* __restrict__ cnt,
                                               const float* __restrict__ w, const float* __restrict__ bias,
                                               float* __restrict__ voxT) {
    __shared__ float msl[3][CIN][256];
    __shared__ float wl[8 * 162];
    int bid = blockIdx.x;                 // b(4) x x(16) x og(8) = 512
    int b = bid >> 7;
    int x = (bid >> 3) & 15;
    int o0 = (bid & 7) * 8;
    int tid = threadIdx.x;
    for (int i = tid; i < 8 * 162; i += 256) wl[i] = w[o0 * 162 + i];
#pragma unroll
    for (int sl = 0; sl < 3; sl++) {
        int xx = x - 1 + sl;
        if (xx >= 0 && xx < 16) {
            float c = cnt[b * S_ + xx * 256 + tid];
            float invc = 1.f / fmaxf(c, 1.f);
#pragma unroll
            for (int i = 0; i < CIN; i++)
                msl[sl][i][tid] = vsum[((size_t)b * CIN + i) * S_ + xx * 256 + tid] * invc;
        } else {
#pragma unroll
            for (int i = 0; i < CIN; i++) msl[sl][i][tid] = 0.f;
        }
    }
    __syncthreads();
    int y = tid >> 4, z = tid & 15;
    float acc[8];
#pragma unroll
    for (int oj = 0; oj < 8; oj++) acc[oj] = bias[o0 + oj];
#pragma unroll
    for (int dx = 0; dx < 3; dx++) {
#pragma unroll
        for (int dy = 0; dy < 3; dy++) {
            int yy = y + dy - 1;
            if ((unsigned)yy >= 16u) continue;
#pragma unroll
            for (int dz = 0; dz < 3; dz++) {
                int zz = z + dz - 1;
                if ((unsigned)zz >= 16u) continue;
                int idx = yy * 16 + zz;
#pragma unroll
                for (int i = 0; i < CIN; i++) {
                    float m = msl[dx][i][idx];
                    int wb = i * 27 + dx * 9 + dy * 3 + dz;
#pragma unroll
                    for (int oj = 0; oj < 8; oj++) acc[oj] += wl[oj * 162 + wb] * m;
                }
            }
        }
    }
    int cell = x * 256 + tid;
    float* dst = voxT + ((size_t)b * S_ + cell) * 64 + o0;
    *(float4*)dst = make_float4(fmaxf(acc[0], 0.f), fmaxf(acc[1], 0.f), fmaxf(acc[2], 0.f), fmaxf(acc[3], 0.f));
    *(float4*)(dst + 4) = make_float4(fmaxf(acc[4], 0.f), fmaxf(acc[5], 0.f), fmaxf(acc[6], 0.f), fmaxf(acc[7], 0.f));
}

// ---------------- K3: qkv via MFMA -> qT,kT [s][64]; vT [c][t] ----------------
__global__ __launch_bounds__(256) void k_qkv4(const float* __restrict__ voxT,
                                              const float* __restrict__ wq, const float* __restrict__ wk,
                                              const float* __restrict__ wv,
                                              unsigned short* __restrict__ qT, unsigned short* __restrict__ kT,
                                              unsigned short* __restrict__ vT) {
    int bid = blockIdx.x;                 // 256: b(4) x chunk(64)
    int b = bid >> 6;
    int srow = (bid & 63) * 64 + (threadIdx.x >> 6) * 16;   // 16 rows per wave
    int lane = threadIdx.x & 63;
    int lo = lane & 15, hi = lane >> 4;

    const float* xr = voxT + ((size_t)b * S_ + srow + lo) * 64 + hi * 8;
    bf16x8 a0 = pack8b(*(const float4*)xr, *(const float4*)(xr + 4));
    bf16x8 a1 = pack8b(*(const float4*)(xr + 32), *(const float4*)(xr + 36));

#pragma unroll
    for (int m = 0; m < 3; m++) {
        const float* wp = (m == 0) ? wq : (m == 1) ? wk : wv;
#pragma unroll
        for (int oc = 0; oc < 4; oc++) {
            const float* wr = wp + (oc * 16 + lo) * 64 + hi * 8;
            bf16x8 b0 = pack8b(*(const float4*)wr, *(const float4*)(wr + 4));
            bf16x8 b1 = pack8b(*(const float4*)(wr + 32), *(const float4*)(wr + 36));
            f32x4 acc = zero4();
            acc = MFMA16(a0, b0, acc);
            acc = MFMA16(a1, b1, acc);
            if (m < 2) {
                unsigned short* dst = ((m == 0) ? qT : kT) + ((size_t)b * S_ + srow + hi * 4) * 64 + oc * 16 + lo;
#pragma unroll
                for (int j = 0; j < 4; j++) dst[(size_t)j * 64] = f2bf(acc[j]);
            } else {
                s16x4 pk;
#pragma unroll
                for (int j = 0; j < 4; j++) pk[j] = (short)f2bf(acc[j]);
                *(s16x4*)(vT + ((size_t)b * 64 + oc * 16 + lo) * S_ + srow + hi * 4) = pk;
            }
        }
    }
}

// ---------------- K4: attn — shared LDS K/V tiles, T14 staging, waves own disjoint 16-row q-tiles ----------------
__global__ __launch_bounds__(256) void k_attn11(const unsigned short* __restrict__ qT,
                                                const unsigned short* __restrict__ kT,
                                                const unsigned short* __restrict__ vT,
                                                float* __restrict__ Opart, float* __restrict__ lpart) {
    __shared__ __align__(16) char Kl[8192];     // 64 t-rows x 128B, XOR-swizzled slots
    __shared__ __align__(16) char Vl[8192];     // 64 c-rows x 128B, XOR-swizzled slots
    __shared__ __align__(16) char PsB[8192];    // per-wave 2KB P buffer
    int bid = blockIdx.x;                       // 512: b(4) x qt(64) x half(2)
    int b = bid >> 7;
    int qt = (bid >> 1) & 63;
    int half = bid & 1;
    int sq0 = qt * 64;
    int tid = threadIdx.x;
    int w = tid >> 6, lane = tid & 63;
    int lo = lane & 15, hi = lane >> 4;
    char* Ps = PsB + w * 2048;

    // Q frags: wave w owns rows sq0 + w*16 .. +15
    const unsigned short* qb = qT + ((size_t)b * S_ + sq0 + w * 16) * 64;
    bf16x8 qf0 = __builtin_bit_cast(bf16x8, *(const short8*)(qb + lo * 64 + hi * 8));
    bf16x8 qf1 = __builtin_bit_cast(bf16x8, *(const short8*)(qb + lo * 64 + hi * 8 + 32));

    f32x4 O[4];
    float l[4];
#pragma unroll
    for (int cc = 0; cc < 4; cc++) O[cc] = zero4();
#pragma unroll
    for (int j = 0; j < 4; j++) l[j] = 0.f;

    const char* kTb = (const char*)(kT + (size_t)b * S_ * 64);   // t-row = 128B
    const char* vTb = (const char*)(vT + (size_t)b * 64 * S_);   // c-row = 8192B
    int tbase = half * 2048;

    // staging offsets for this thread
    int swz = ((tid >> 3) & 7) << 4;
    int x0 = tid * 16;                    // chunk byte 0..4095
    int vrow = tid >> 3, vslot16 = (tid & 7) * 16;

    // prologue: issue loads for tile 0
    short8 g0, g1, g2, g3;
    {
        const char* ktile = kTb + (size_t)tbase * 128;
        g0 = *(const short8*)(ktile + x0);
        g1 = *(const short8*)(ktile + x0 + 4096);
        const char* vt0 = vTb + (size_t)tbase * 2;
        g2 = *(const short8*)(vt0 + (size_t)vrow * 8192 + vslot16);
        g3 = *(const short8*)(vt0 + (size_t)(vrow + 32) * 8192 + vslot16);
    }

    for (int it = 0; it < 32; ++it) {
        __syncthreads();                           // prior compute's LDS reads done
        // write staged tile (waits vmcnt for g implicitly)
        *(short8*)(Kl + (x0 ^ swz)) = g0;
        *(short8*)(Kl + ((x0 + 4096) ^ swz)) = g1;
        *(short8*)(Vl + (x0 ^ swz)) = g2;
        *(short8*)(Vl + ((x0 + 4096) ^ swz)) = g3;
        __syncthreads();                           // tile visible to all waves
        // issue loads for next tile: they fly under this tile's compute
        if (it + 1 < 32) {
            int t0n = tbase + (it + 1) * 64;
            const char* ktile = kTb + (size_t)t0n * 128;
            g0 = *(const short8*)(ktile + x0);
            g1 = *(const short8*)(ktile + x0 + 4096);
            const char* vtn = vTb + (size_t)t0n * 2;
            g2 = *(const short8*)(vtn + (size_t)vrow * 8192 + vslot16);
            g3 = *(const short8*)(vtn + (size_t)(vrow + 32) * 8192 + vslot16);
        }
        // ---- QK^T + fixed-max softmax (16 q-rows per wave) ----
#pragma unroll
        for (int ct = 0; ct < 4; ct++) {
            int t = ct * 16 + lo;
            int tswz = (t & 7) << 4;
            bf16x8 kf0 = __builtin_bit_cast(bf16x8, *(const short8*)(Kl + (t * 128 + ((hi * 16) ^ tswz))));
            bf16x8 kf1 = __builtin_bit_cast(bf16x8, *(const short8*)(Kl + (t * 128 + ((64 + hi * 16) ^ tswz))));
            f32x4 z = zero4();
            z = MFMA16(qf0, kf0, z);
            f32x4 Sacc = MFMA16(qf1, kf1, z);
#pragma unroll
            for (int j = 0; j < 4; j++) {
                float p = __expf(Sacc[j] * 0.125f);
                l[j] += p;
                int r = hi * 4 + j;
                int pswz = (r & 7) << 4;
                *(unsigned short*)(Ps + ((r * 128 + t * 2) ^ pswz)) = f2bf(p);
            }
        }
        // ---- PV (P same-wave in LDS; V from shared tile) ----
        int rswz = (lo & 7) << 4;
        bf16x8 pa0 = __builtin_bit_cast(bf16x8, *(const short8*)(Ps + ((lo * 128 + hi * 16) ^ rswz)));
        bf16x8 pa1 = __builtin_bit_cast(bf16x8, *(const short8*)(Ps + ((lo * 128 + 64 + hi * 16) ^ rswz)));
#pragma unroll
        for (int cc = 0; cc < 4; cc++) {
            int c = cc * 16 + lo;
            int cswz = (c & 7) << 4;
            bf16x8 vf0 = __builtin_bit_cast(bf16x8, *(const short8*)(Vl + (c * 128 + ((hi * 16) ^ cswz))));
            bf16x8 vf1 = __builtin_bit_cast(bf16x8, *(const short8*)(Vl + (c * 128 + ((64 + hi * 16) ^ cswz))));
            O[cc] = MFMA16(pa0, vf0, O[cc]);
            O[cc] = MFMA16(pa1, vf1, O[cc]);
        }
    }

    // ---- epilogue: each wave writes its own 16 rows (no combine) ----
    float* ob = Opart + ((size_t)(half * B_ + b) * S_ + sq0 + w * 16) * 64;
#pragma unroll
    for (int cc = 0; cc < 4; cc++)
#pragma unroll
        for (int j = 0; j < 4; j++)
            ob[(size_t)(hi * 4 + j) * 64 + cc * 16 + lo] = O[cc][j];
#pragma unroll
    for (int j = 0; j < 4; j++) {
        float s = l[j];
        s += __shfl_xor(s, 1);
        s += __shfl_xor(s, 2);
        s += __shfl_xor(s, 4);
        s += __shfl_xor(s, 8);
        if (lo == 0)
            lpart[(size_t)(half * B_ + b) * S_ + sq0 + w * 16 + hi * 4 + j] = s;
    }
}

// ---------------- K5: combine(2 halves) + Wo MFMA + residual + SE-mean -> xattT bf16 ----------------
__global__ __launch_bounds__(256) void k_wo_mfma(const float* __restrict__ Opart,
                                                 const float* __restrict__ lpart,
                                                 const float* __restrict__ wo,
                                                 const float* __restrict__ voxT,
                                                 unsigned short* __restrict__ xattT,
                                                 float* __restrict__ semean) {
    __shared__ float sem[64];
    int tid = threadIdx.x;
    if (tid < 64) sem[tid] = 0.f;
    __syncthreads();
    int wid = tid >> 6, lane = tid & 63;
    int lo = lane & 15, hi = lane >> 4;
    int r0 = blockIdx.x * 64 + wid * 16;               // global row (b*S + s)
    int bidx = r0 >> 12;
    int row = r0 + lo;
    const int BS = B_ * S_;

    float L = lpart[row] + lpart[BS + row];
    float inv = 1.f / L;
    float4 q0 = make_float4(0.f, 0.f, 0.f, 0.f), q1 = q0, q2 = q0, q3 = q0;
#pragma unroll
    for (int sp = 0; sp < 2; sp++) {
        const float* orow = Opart + ((size_t)sp * BS + row) * 64 + hi * 8;
        float4 t0 = *(const float4*)(orow);
        float4 t1 = *(const float4*)(orow + 4);
        float4 t2 = *(const float4*)(orow + 32);
        float4 t3 = *(const float4*)(orow + 36);
        q0.x += t0.x; q0.y += t0.y; q0.z += t0.z; q0.w += t0.w;
        q1.x += t1.x; q1.y += t1.y; q1.z += t1.z; q1.w += t1.w;
        q2.x += t2.x; q2.y += t2.y; q2.z += t2.z; q2.w += t2.w;
        q3.x += t3.x; q3.y += t3.y; q3.z += t3.z; q3.w += t3.w;
    }
    q0.x *= inv; q0.y *= inv; q0.z *= inv; q0.w *= inv;
    q1.x *= inv; q1.y *= inv; q1.z *= inv; q1.w *= inv;
    q2.x *= inv; q2.y *= inv; q2.z *= inv; q2.w *= inv;
    q3.x *= inv; q3.y *= inv; q3.z *= inv; q3.w *= inv;
    bf16x8 a0 = pack8b(q0, q1);
    bf16x8 a1 = pack8b(q2, q3);

    float colsum[4];
#pragma unroll
    for (int cc = 0; cc < 4; cc++) {
        int o = cc * 16 + lo;
        float4 f0 = *(const float4*)(wo + o * 64 + hi * 8);
        float4 f1 = *(const float4*)(wo + o * 64 + hi * 8 + 4);
        bf16x8 b0 = pack8b(f0, f1);
        float4 f2 = *(const float4*)(wo + o * 64 + 32 + hi * 8);
        float4 f3 = *(const float4*)(wo + o * 64 + 32 + hi * 8 + 4);
        bf16x8 b1 = pack8b(f2, f3);
        f32x4 acc = zero4();
        acc = MFMA16(a0, b0, acc);
        acc = MFMA16(a1, b1, acc);
        float cs = 0.f;
#pragma unroll
        for (int j = 0; j < 4; j++) {
            size_t idx = (size_t)(r0 + hi * 4 + j) * 64 + o;
            float xn = acc[j] + voxT[idx];
            xattT[idx] = f2bf(xn);
            cs += xn;
        }
        cs += __shfl_xor(cs, 16);
        cs += __shfl_xor(cs, 32);
        colsum[cc] = cs;
    }
    if (hi == 0) {
#pragma unroll
        for (int cc = 0; cc < 4; cc++) atomicAdd(&sem[cc * 16 + lo], colsum[cc]);
    }
    __syncthreads();
    if (tid < 64) atomicAdd(&semean[bidx * 64 + tid], sem[tid]);
}

// ---------------- K8: SE gate + devoxelize (bf16 gather) + point MLP + MFMA classifier ----------------
__global__ __launch_bounds__(256) void k_point(const float* __restrict__ coords, const float* __restrict__ feats,
                                               const unsigned short* __restrict__ xt, const float* __restrict__ semean,
                                               const float* __restrict__ sw1, const float* __restrict__ sb1,
                                               const float* __restrict__ sw2, const float* __restrict__ sb2,
                                               const float* __restrict__ pw,
                                               const float* __restrict__ pb, const float* __restrict__ w1,
                                               const float* __restrict__ b1, const float* __restrict__ w2,
                                               const float* __restrict__ b2, float* __restrict__ out) {
    __shared__ unsigned short fl[256 * 64];    // 32KB fused bf16, XOR-swizzled rows
    __shared__ float pwl[64 * 6];
    __shared__ float pbl[64];
    __shared__ float b1l[128];
    __shared__ float w2l[3 * 128];
    __shared__ float b2l[3];
    __shared__ float gl[64];
    __shared__ float sml[64];
    __shared__ float hh[8];
    int tid = threadIdx.x;
    int gidx0 = blockIdx.x * 256;
    int b = gidx0 >> 15, n0 = gidx0 & (N_ - 1);
    int n = n0 + tid;
    for (int i = tid; i < 384; i += 256) { pwl[i] = pw[i]; w2l[i] = w2[i]; }
    if (tid < 128) b1l[tid] = b1[tid];
    if (tid < 64) { pbl[tid] = pb[tid]; sml[tid] = semean[b * 64 + tid] * (1.0f / S_); }
    if (tid < 3) b2l[tid] = b2[tid];
    __syncthreads();
    if (tid < 8) {
        float a = sb1[tid];
#pragma unroll
        for (int i = 0; i < 64; i++) a += sw1[tid * 64 + i] * sml[i];
        hh[tid] = fmaxf(a, 0.f);
    }
    __syncthreads();
    if (tid < 64) {
        float g = sb2[tid];
#pragma unroll
        for (int j = 0; j < 8; j++) g += sw2[tid * 8 + j] * hh[j];
        gl[tid] = 1.f / (1.f + __expf(-g));
    }
    __syncthreads();

    const float* cb = coords + (size_t)b * 3 * N_;
    float px = fminf(fmaxf(cb[n] * R_ - 0.5f, 0.f), 15.f);
    float py = fminf(fmaxf(cb[N_ + n] * R_ - 0.5f, 0.f), 15.f);
    float pz = fminf(fmaxf(cb[2 * N_ + n] * R_ - 0.5f, 0.f), 15.f);
    int x0 = (int)floorf(px); float wx = px - x0; int x1 = min(x0 + 1, 15);
    int y0 = (int)floorf(py); float wy = py - y0; int y1 = min(y0 + 1, 15);
    int z0 = (int)floorf(pz); float wz = pz - z0; int z1 = min(z0 + 1, 15);
    float fused[64];
#pragma unroll
    for (int c = 0; c < 64; c++) fused[c] = 0.f;
    const unsigned short* xb = xt + (size_t)b * S_ * 64;
#pragma unroll
    for (int dx = 0; dx < 2; dx++) {
#pragma unroll
        for (int dy = 0; dy < 2; dy++) {
#pragma unroll
            for (int dz = 0; dz < 2; dz++) {
                int xi = dx ? x1 : x0, yi = dy ? y1 : y0, zi = dz ? z1 : z0;
                float wgt = (dx ? wx : 1.f - wx) * (dy ? wy : 1.f - wy) * (dz ? wz : 1.f - wz);
                const short8* g = (const short8*)(xb + (size_t)((xi * 16 + yi) * 16 + zi) * 64);
#pragma unroll
                for (int c8 = 0; c8 < 8; c8++) {
                    short8 gv = g[c8];
#pragma unroll
                    for (int i = 0; i < 8; i++)
                        fused[c8 * 8 + i] += wgt * bf2f((unsigned short)gv[i]);
                }
            }
        }
    }
    float fv[6];
#pragma unroll
    for (int i = 0; i < 6; i++) fv[i] = feats[((size_t)b * 6 + i) * N_ + n];
#pragma unroll
    for (int c = 0; c < 64; c++) {
        float pt = pbl[c];
#pragma unroll
        for (int i = 0; i < 6; i++) pt += pwl[c * 6 + i] * fv[i];
        pt = fmaxf(pt, 0.f);
        fused[c] = fmaxf(fused[c] * gl[c] + pt, 0.f);
    }
#pragma unroll
    for (int ch = 0; ch < 8; ch++) {
        short8 v;
#pragma unroll
        for (int i = 0; i < 8; i++) v[i] = (short)f2bf(fused[ch * 8 + i]);
        int byte = tid * 128 + ch * 16;
        *(short8*)((char*)fl + (byte ^ ((tid & 7) << 4))) = v;
    }
    __syncthreads();

    int wv = tid >> 6, lane = tid & 63;
    int lo = lane & 15, hi = lane >> 4;
    bf16x8 bw[16];
#pragma unroll
    for (int th = 0; th < 8; th++) {
#pragma unroll
        for (int kf = 0; kf < 2; kf++) {
            const float* wr = w1 + (th * 16 + lo) * 64 + kf * 32 + hi * 8;
            bw[th * 2 + kf] = pack8b(*(const float4*)wr, *(const float4*)(wr + 4));
        }
    }
#pragma unroll
    for (int g = 0; g < 4; g++) {
        int row = wv * 64 + g * 16 + lo;
        int swz = (row & 7) << 4;
        bf16x8 a0 = __builtin_bit_cast(bf16x8, *(const short8*)((char*)fl + ((row * 128 + hi * 16) ^ swz)));
        bf16x8 a1 = __builtin_bit_cast(bf16x8, *(const short8*)((char*)fl + ((row * 128 + 64 + hi * 16) ^ swz)));
        f32x4 acc[8];
#pragma unroll
        for (int th = 0; th < 8; th++) {
            acc[th] = zero4();
            acc[th] = MFMA16(a0, bw[th * 2], acc[th]);
            acc[th] = MFMA16(a1, bw[th * 2 + 1], acc[th]);
        }
        float s0[4] = {0.f, 0.f, 0.f, 0.f};
        float s1[4] = {0.f, 0.f, 0.f, 0.f};
        float s2[4] = {0.f, 0.f, 0.f, 0.f};
#pragma unroll
        for (int th = 0; th < 8; th++) {
            int hidx = th * 16 + lo;
            float w2o0 = w2l[hidx];
            float w2o1 = w2l[128 + hidx];
            float w2o2 = w2l[256 + hidx];
            float bias = b1l[hidx];
#pragma unroll
            for (int j = 0; j < 4; j++) {
                float hj = fmaxf(acc[th][j] + bias, 0.f);
                s0[j] += hj * w2o0;
                s1[j] += hj * w2o1;
                s2[j] += hj * w2o2;
            }
        }
#pragma unroll
        for (int j = 0; j < 4; j++) {
            s0[j] += __shfl_xor(s0[j], 1); s0[j] += __shfl_xor(s0[j], 2);
            s0[j] += __shfl_xor(s0[j], 4); s0[j] += __shfl_xor(s0[j], 8);
            s1[j] += __shfl_xor(s1[j], 1); s1[j] += __shfl_xor(s1[j], 2);
            s1[j] += __shfl_xor(s1[j], 4); s1[j] += __shfl_xor(s1[j], 8);
            s2[j] += __shfl_xor(s2[j], 1); s2[j] += __shfl_xor(s2[j], 2);
            s2[j] += __shfl_xor(s2[j], 4); s2[j] += __shfl_xor(s2[j], 8);
        }
        int nbase = n0 + wv * 64 + g * 16 + hi * 4;
        if (lo == 0) {
            float4 o4 = make_float4(s0[0] + b2l[0], s0[1] + b2l[0], s0[2] + b2l[0], s0[3] + b2l[0]);
            *(float4*)(out + ((size_t)b * 3 + 0) * N_ + nbase) = o4;
        } else if (lo == 1) {
            float4 o4 = make_float4(s1[0] + b2l[1], s1[1] + b2l[1], s1[2] + b2l[1], s1[3] + b2l[1]);
            *(float4*)(out + ((size_t)b * 3 + 1) * N_ + nbase) = o4;
        } else if (lo == 2) {
            float4 o4 = make_float4(s2[0] + b2l[2], s2[1] + b2l[2], s2[2] + b2l[2], s2[3] + b2l[2]);
            *(float4*)(out + ((size_t)b * 3 + 2) * N_ + nbase) = o4;
        }
    }
}

extern "C" void kernel_launch(void* const* d_in, const int* in_sizes, int n_in,
                              void* d_out, int out_size, void* d_ws, size_t ws_size,
                              hipStream_t stream) {
    const float* coords  = (const float*)d_in[0];
    const float* feats   = (const float*)d_in[1];
    const float* conv_w  = (const float*)d_in[2];
    const float* conv_b  = (const float*)d_in[3];
    const float* wq      = (const float*)d_in[4];
    const float* wk      = (const float*)d_in[5];
    const float* wv      = (const float*)d_in[6];
    const float* wo      = (const float*)d_in[7];
    const float* se_w1   = (const float*)d_in[8];
    const float* se_b1   = (const float*)d_in[9];
    const float* se_w2   = (const float*)d_in[10];
    const float* se_b2   = (const float*)d_in[11];
    const float* point_w = (const float*)d_in[12];
    const float* point_b = (const float*)d_in[13];
    const float* cls_w1  = (const float*)d_in[14];
    const float* cls_b1  = (const float*)d_in[15];
    const float* cls_w2  = (const float*)d_in[16];
    const float* cls_b2  = (const float*)d_in[17];

    float* ws = (float*)d_ws;
    float* vsum   = ws;                        // 98304
    float* cnt    = ws + 98304;                // 16384
    float* semean = ws + 114688;               // 256
    float* vox    = ws + 115200;               // region reused as xattT (bf16)
    float* voxT   = vox + 1048576;             // f32 [b][s][64]: conv2 -> qkv4 + wo residual
    unsigned short* qT = (unsigned short*)(voxT + 1048576);
    unsigned short* kT = qT + 1048576;
    unsigned short* vT = kT + 1048576;
    float* Opart  = (float*)(vT + 1048576);    // 2 halves x 16384 x 64 = 2097152 f32
    float* lpart  = Opart + 2097152;           // 32768
    unsigned short* xattT = (unsigned short*)vox;   // bf16 [b][s][64]

    hipMemsetAsync(ws, 0, 114944 * sizeof(float), stream);    // vsum + cnt + semean
    k_voxelize<<<512, 256, 0, stream>>>(coords, feats, vsum, cnt);
    k_conv2<<<512, 256, 0, stream>>>(vsum, cnt, conv_w, conv_b, voxT);
    k_qkv4<<<256, 256, 0, stream>>>(voxT, wq, wk, wv, qT, kT, vT);
    k_attn11<<<512, 256, 0, stream>>>(qT, kT, vT, Opart, lpart);
    k_wo_mfma<<<256, 256, 0, stream>>>(Opart, lpart, wo, voxT, xattT, semean);
    k_point<<<512, 256, 0, stream>>>(coords, feats, xattT, semean,
                                     se_w1, se_b1, se_w2, se_b2, point_w, point_b,
                                     cls_w1, cls_b1, cls_w2, cls_b2, (float*)d_out);
}